// Round 20
// baseline (2122.768 us; speedup 1.0000x reference)
//
#include <hip/hip_runtime.h>
#include <stdint.h>
#include <math.h>

#define NB   16
#define HF   128
#define WF   128
#define NA   9
#define HW   (HF*WF)          // 16384
#define NTOT (HW*NA)          // 147456
#define PRE  12000
#define POST 2000
#define CAP  16384

// fixed ws offsets (bytes); diag + M planes follow, sized by CHUNK at runtime
#define OFF_HIST  0u
#define SZ_HIST   (NB*65536u*4u)            // 4,194,304
#define OFF_META  (OFF_HIST + SZ_HIST)
#define SZ_META   4096u   // words: [0..15] cutoff | [32..47] nk | [256+b*16] gather count
#define OFF_CAND  (OFF_META + SZ_META)
#define SZ_CAND   (NB*CAP*8u)               // 2,097,152
#define OFF_TB    (OFF_CAND + SZ_CAND)
#define SZ_TB     (5u*NB*PRE*4u)            // 3,840,000
#define OFF_KEEP  (OFF_TB + SZ_TB)
#define SZ_KEEP   (NB*POST*4u)              // 128,000
#define OFF_PRES  (OFF_KEEP + SZ_KEEP)
#define SZ_PRES   (NB*64u*8u)               // 8,192 (max NW=64)
#define OFF_M     (OFF_PRES + SZ_PRES)      // = 10,271,744 (16B aligned)
#define SZ_KBOX   (5u*NB*POST*4u)           // 640,000

#define M_CNT(b)  (256 + (b)*16)

// base anchors = classic py-faster-rcnn table minus 1 (base [0,0,15,15]); a8.y2=359.
__constant__ float c_ax1[NA] = {-84.f,-176.f,-360.f,-56.f,-120.f,-248.f,-36.f,-80.f,-168.f};
__constant__ float c_ay1[NA] = {-40.f,-88.f,-184.f,-56.f,-120.f,-248.f,-80.f,-168.f,-344.f};
__constant__ float c_ax2[NA] = { 99.f, 191.f, 375.f, 71.f, 135.f, 263.f, 51.f, 95.f, 183.f};
__constant__ float c_ay2[NA] = { 55.f, 103.f, 199.f, 71.f, 135.f, 263.f, 95.f, 183.f, 359.f};

__device__ __forceinline__ uint32_t score_key(float f){
  uint32_t b = __float_as_uint(f);
  uint32_t u = (b & 0x80000000u) ? ~b : (b | 0x80000000u);
  return ~u;
}

__device__ __forceinline__ bool iou_gt(float ax1,float ay1,float ax2,float ay2,float aa,
                                       float bx1,float by1,float bx2,float by2,float ba){
  float xx1 = fmaxf(ax1,bx1);
  float yy1 = fmaxf(ay1,by1);
  float xx2 = fminf(ax2,bx2);
  float yy2 = fminf(ay2,by2);
  float w = fmaxf(__fadd_rn(__fsub_rn(xx2,xx1),1.0f), 0.0f);
  float h = fmaxf(__fadd_rn(__fsub_rn(yy2,yy1),1.0f), 0.0f);
  float inter = __fmul_rn(w,h);
  float denom = __fsub_rn(__fadd_rn(aa,ba), inter);
  float iou   = __fdiv_rn(inter, denom);
  return iou > 0.7f;
}

// -------- pass 1: histogram (+ zero presup) --------
__global__ void prep_k(const float* __restrict__ scores, uint32_t* __restrict__ hist,
                       uint64_t* __restrict__ presup){
  if (blockIdx.x == 0 && threadIdx.x < 256){
    #pragma unroll
    for (int k=0;k<4;k++) presup[threadIdx.x*4+k] = 0ULL;
  }
  int g = blockIdx.x*256 + threadIdx.x;
  if (g >= NB*NTOT) return;
  int hw = g & (HW-1);
  int t  = g >> 14;
  int ch = t % NA;
  int b  = t / NA;
  float s = scores[((size_t)(b*2*NA + NA + ch) << 14) + hw];
  uint32_t k = score_key(s);
  atomicAdd(&hist[((uint32_t)b<<16) + (k>>16)], 1u);
}

// -------- pass 2: cutoff --------
__global__ __launch_bounds__(1024) void scanhist_k(const uint32_t* __restrict__ hist,
                                                   uint32_t* __restrict__ meta){
  int b = blockIdx.x, t = threadIdx.x;
  const uint32_t* hh = hist + ((uint32_t)b<<16);
  int base = t<<6;
  uint32_t s=0;
  for (int i=0;i<64;i++) s += hh[base+i];
  __shared__ uint32_t part[1024];
  part[t]=s; __syncthreads();
  for (int off=1; off<1024; off<<=1){
    uint32_t v = (t>=off)? part[t-off] : 0u;
    __syncthreads();
    part[t] += v;
    __syncthreads();
  }
  uint32_t incl = part[t], excl = incl - s;
  if (excl < PRE && incl >= PRE){
    uint32_t run = excl;
    for (int i=0;i<64;i++){
      run += hh[base+i];
      if (run >= PRE){ meta[b] = (uint32_t)(base+i); break; }
    }
  }
}

// -------- pass 3: gather (block-aggregated atomics) --------
__global__ __launch_bounds__(256) void gather_k(const float* __restrict__ scores,
                                                uint32_t* __restrict__ meta,
                                                uint64_t* __restrict__ cand){
  int g = blockIdx.x*256 + threadIdx.x;
  int hw = g & (HW-1);
  int t  = g >> 14;
  int ch = t % NA;
  int b  = t / NA;
  float s = scores[((size_t)(b*2*NA + NA + ch) << 14) + hw];
  uint32_t k = score_key(s);
  bool sel = (k>>16) <= meta[b];
  unsigned long long m = __ballot(sel);
  int wid  = threadIdx.x >> 6;
  int lane = threadIdx.x & 63;
  __shared__ uint32_t woff[4];
  __shared__ uint32_t sbase;
  if (lane==0) woff[wid] = __popcll(m);
  __syncthreads();
  if (threadIdx.x==0){
    uint32_t a=0;
    #pragma unroll
    for (int i=0;i<4;i++){ uint32_t c=woff[i]; woff[i]=a; a+=c; }
    sbase = a ? atomicAdd(&meta[M_CNT(b)], a) : 0u;
  }
  __syncthreads();
  if (sel){
    uint32_t pos = sbase + woff[wid] + (uint32_t)__popcll(m & ((1ULL<<lane)-1ULL));
    if (pos < CAP){
      uint32_t idx = (uint32_t)hw*NA + (uint32_t)ch;
      cand[((size_t)b<<14) + pos] = ((uint64_t)k << 18) | (uint64_t)idx;
    }
  }
}

// ======== pass 4a: per-2048-chunk LDS bitonic sort (k=2..2048) ========
__global__ __launch_bounds__(256) void bsort_local_k(uint64_t* __restrict__ buf){
  __shared__ uint64_t S[2048];
  int blk = blockIdx.x;
  int b = blk>>3, chunk = blk&7;
  uint64_t* A_ = buf + ((size_t)b<<14) + ((size_t)chunk<<11);
  int t = threadIdx.x;
  int gbase = chunk<<11;
  for (int i=t;i<2048;i+=256) S[i]=A_[i];
  __syncthreads();
  for (unsigned k=2;k<=2048u;k<<=1){
    for (unsigned j=k>>1;j>0;j>>=1){
      for (int i=t;i<2048;i+=256){
        int l = i ^ (int)j;
        if (l > i){
          bool asc = (((gbase+i) & (int)k)==0);
          uint64_t a=S[i], c=S[l];
          bool sw = asc ? (a>c) : (a<c);
          if (sw){ S[i]=c; S[l]=a; }
        }
      }
      __syncthreads();
    }
  }
  for (int i=t;i<2048;i+=256) A_[i]=S[i];
}

// ======== pass 4b: finish sort (k=4096..16384) + inline extract (1 block/batch) ========
__global__ __launch_bounds__(1024) void bsort_gfin_k(uint64_t* __restrict__ buf,
                                                     const float* __restrict__ deltas,
                                                     const float* __restrict__ iminfo,
                                                     float* __restrict__ tb){
  __shared__ uint64_t S[2048];
  int b = blockIdx.x;
  uint64_t* A_ = buf + ((size_t)b<<14);
  int t = threadIdx.x;
  for (int k = 4096; k <= 16384; k <<= 1){
    for (int j = k>>1; j >= 2048; j >>= 1){
      for (int q = t; q < 8192; q += 1024){
        int i = ((q & ~(j-1))<<1) | (q & (j-1));
        int l = i + j;
        uint64_t a = A_[i], c = A_[l];
        bool asc = ((i & k)==0);
        if (asc ? (a>c) : (a<c)){ A_[i]=c; A_[l]=a; }
      }
      __syncthreads();
    }
    for (int c0 = 0; c0 < 8; c0++){
      uint64_t* C_ = A_ + (c0<<11);
      S[t] = C_[t]; S[t+1024] = C_[t+1024];
      __syncthreads();
      bool asc = (((c0<<11) & k)==0);
      for (int j = 1024; j >= 1; j >>= 1){
        int i = ((t & ~(j-1))<<1) | (t & (j-1));
        int l = i + j;
        uint64_t a=S[i], c=S[l];
        if (asc ? (a>c) : (a<c)){ S[i]=c; S[l]=a; }
        __syncthreads();
      }
      C_[t] = S[t]; C_[t+1024] = S[t+1024];
      __syncthreads();
    }
  }
  float maxx = __fsub_rn(iminfo[b*3+1],1.f);
  float maxy = __fsub_rn(iminfo[b*3+0],1.f);
  for (int j = t; j < PRE; j += 1024){
    uint64_t K = A_[j];
    uint32_t idx = (uint32_t)K & 0x3FFFFu;
    int ch = (int)(idx % NA);
    int hw = (int)(idx / NA);
    int w  = hw & (WF-1);
    int h  = hw >> 7;
    float sx = (float)(w*16), sy = (float)(h*16);
    float ax1 = c_ax1[ch]+sx, ay1 = c_ay1[ch]+sy, ax2 = c_ax2[ch]+sx, ay2 = c_ay2[ch]+sy;
    const float* dp = deltas + ((size_t)(b*4*NA + ch*4) << 14) + hw;
    float dx = dp[0], dy = dp[HW], dwv = dp[2*HW], dhv = dp[3*HW];
    float aw  = __fadd_rn(__fsub_rn(ax2,ax1),1.f);
    float ah  = __fadd_rn(__fsub_rn(ay2,ay1),1.f);
    float acx = __fadd_rn(ax1, __fmul_rn(0.5f,aw));
    float acy = __fadd_rn(ay1, __fmul_rn(0.5f,ah));
    float pcx = __fadd_rn(__fmul_rn(dx,aw), acx);
    float pcy = __fadd_rn(__fmul_rn(dy,ah), acy);
    float ew  = (float)exp((double)dwv);
    float eh  = (float)exp((double)dhv);
    float pw  = __fmul_rn(ew, aw);
    float ph  = __fmul_rn(eh, ah);
    float hx  = __fmul_rn(0.5f,pw), hy = __fmul_rn(0.5f,ph);
    float x1 = __fsub_rn(pcx,hx), y1 = __fsub_rn(pcy,hy);
    float x2 = __fadd_rn(pcx,hx), y2 = __fadd_rn(pcy,hy);
    x1 = fminf(fmaxf(x1,0.f),maxx); y1 = fminf(fmaxf(y1,0.f),maxy);
    x2 = fminf(fmaxf(x2,0.f),maxx); y2 = fminf(fmaxf(y2,0.f),maxy);
    float area = __fmul_rn(__fadd_rn(__fsub_rn(x2,x1),1.f), __fadd_rn(__fsub_rn(y2,y1),1.f));
    int o = b*PRE + j;
    tb[o]            = x1;
    tb[NB*PRE + o]   = y1;
    tb[2*NB*PRE + o] = x2;
    tb[3*NB*PRE + o] = y2;
    tb[4*NB*PRE + o] = area;
  }
}

// -------- NMS phase a: 2D-tiled cross (cand-tile x keep-tile), atomicOr merge --------
template<int CH>
__global__ __launch_bounds__(256) void cross2_k(const float* __restrict__ tb,
                                                const float* __restrict__ kbox,
                                                const uint32_t* __restrict__ meta,
                                                uint64_t* __restrict__ presup,
                                                int base){
  constexpr int NW = CH/64;
  int b  = blockIdx.z;
  int nk = (int)meta[32+b];
  int kt = blockIdx.y*256;
  if (kt >= nk) return;
  __shared__ float kx1[256],ky1[256],kx2[256],ky2[256],kar[256];
  int tt = threadIdx.x;
  int kk = kt + tt;
  if (kk < nk){
    int o = b*POST + kk;
    kx1[tt]=kbox[o];
    ky1[tt]=kbox[NB*POST+o];
    kx2[tt]=kbox[2*NB*POST+o];
    ky2[tt]=kbox[3*NB*POST+o];
    kar[tt]=kbox[4*NB*POST+o];
  }
  __syncthreads();
  int jl = blockIdx.x*256 + tt;
  int j  = base + jl;
  bool supp = false;
  if (j < PRE){
    int o = b*PRE + j;
    float x1=tb[o], y1=tb[NB*PRE+o], x2=tb[2*NB*PRE+o], y2=tb[3*NB*PRE+o], ar=tb[4*NB*PRE+o];
    int lim = min(256, nk-kt);
    for (int q=0;q<lim;q++){
      if (iou_gt(kx1[q],ky1[q],kx2[q],ky2[q],kar[q], x1,y1,x2,y2,ar)){ supp=true; break; }
    }
  }
  unsigned long long m = __ballot(supp);
  if ((tt & 63)==0 && m)
    atomicOr((unsigned long long*)&presup[b*NW + (jl>>6)], m);
}

// -------- fused: scan(phase p) with diag-sidecar ∥ intra(phase p+1) --------
template<int CH>
__global__ __launch_bounds__(256) void fused_k(const uint64_t* __restrict__ Mscan,
                                               const uint64_t* __restrict__ diagc,
                                               uint64_t* __restrict__ Mnext,
                                               uint64_t* __restrict__ diagn,
                                               uint64_t* __restrict__ presup,
                                               uint32_t* __restrict__ keep,
                                               uint32_t* __restrict__ meta,
                                               const float* __restrict__ tb,
                                               float* __restrict__ kbox,
                                               float* __restrict__ outp,
                                               int base_scan, int base_next, int nscan,
                                               int dofinal){
  constexpr int NW    = CH/64;     // words per row
  constexpr int UNITS = CH/256;    // intra blocks per batch
  __shared__ __align__(16) char smem[40960];
  __shared__ int s_nk;
  int t = threadIdx.x;

  if ((int)blockIdx.x < nscan){
    // ===== scan role: diag-sidecar keep chain (bit-identical decisions) =====
    uint64_t* sdiag = (uint64_t*)smem;         // CH*8 bytes (<=32KB)
    int b = blockIdx.x;
    int l = t & 63, wv = t >> 6;
    const uint64_t* Mb = Mscan + (size_t)b*CH*NW;
    for (int i=t; i<CH; i+=256) sdiag[i] = diagc[(size_t)b*CH + i];
    __syncthreads();
    int nk0 = (int)meta[32+b];
    int nk = nk0;
    if (wv==0){
      uint64_t acc = (l<NW) ? presup[b*NW + l] : ~0ULL;
      for (int w=0; w<NW; w++){
        if (nk >= POST) break;
        uint64_t tile = sdiag[(w<<6) + l];     // lane l: diag word of row w*64+l
        uint64_t cur  = __shfl(acc, w);
        uint64_t kmask = 0;
        while (cur != ~0ULL && nk < POST){
          int p = __ffsll((unsigned long long)(~cur)) - 1;
          if (l==0) keep[b*POST+nk] = (uint32_t)(base_scan + (w<<6) + p);
          nk++;
          kmask |= (1ULL<<p);
          cur |= (1ULL<<p) | (uint64_t)__shfl(tile, p);   // register bpermute on chain
        }
        // batched row-OR from global M (off-chain, 16 in flight)
        while (kmask){
          int ps[16];
          #pragma unroll
          for (int i2=0;i2<16;i2++){
            if (kmask){ ps[i2] = __ffsll((unsigned long long)kmask)-1; kmask &= kmask-1ULL; }
            else ps[i2] = -1;
          }
          uint64_t r = 0;
          #pragma unroll
          for (int i2=0;i2<16;i2++){
            uint64_t v = (ps[i2]>=0 && l<NW) ? Mb[(size_t)((w<<6)+ps[i2])*NW + l] : 0ULL;
            r |= v;
          }
          acc |= r;
        }
      }
      if (l==0){ meta[32+b] = (uint32_t)nk; s_nk = nk; }
      // re-init presup for the NEXT chunk with validity bits (cross2 atomicOrs on top)
      if (l<NW){
        long rem = (long)PRE - (long)(base_next + (l<<6));
        uint64_t v = (rem >= 64) ? 0ULL : ((rem <= 0) ? ~0ULL : ~((1ULL<<rem) - 1ULL));
        presup[b*NW + l] = v;
      }
    }
    __syncthreads();
    int nkf = s_nk;
    for (int i = nk0 + t; i < nkf; i += 256){
      int j = (int)keep[b*POST+i];
      int o = b*PRE + j;
      int d = b*POST + i;
      kbox[d]            = tb[o];
      kbox[NB*POST + d]  = tb[NB*PRE+o];
      kbox[2*NB*POST + d]= tb[2*NB*PRE+o];
      kbox[3*NB*POST + d]= tb[3*NB*PRE+o];
      kbox[4*NB*POST + d]= tb[4*NB*PRE+o];
    }
    if (dofinal){
      for (int i = t; i < POST; i += 256){
        float x1=0.f,y1=0.f,x2=0.f,y2=0.f;
        if (i < nkf){
          int j = (int)keep[b*POST+i];
          int o = b*PRE + j;
          x1=tb[o]; y1=tb[NB*PRE+o]; x2=tb[2*NB*PRE+o]; y2=tb[3*NB*PRE+o];
        }
        float* op = outp + (size_t)(b*POST+i)*5;
        op[0]=(float)b; op[1]=x1; op[2]=y1; op[3]=x2; op[4]=y2;
      }
    }
  } else {
    // ===== intra role: bit-matrix for phase p+1, windowed columns + diag sidecar =====
    float4* sbx = (float4*)smem;               // 32 KB (2048 col boxes)
    float*  sar = (float*)(smem + 32768);      // 8 KB
    int bid = (int)blockIdx.x - nscan;
    int b  = bid / UNITS;
    int il = (bid % UNITS)*256 + t;
    int base = base_next;
    int i = base + il;
    bool valid = (i < PRE);
    float4 bb = make_float4(0.f,0.f,0.f,0.f);
    float  ar = 1.f;
    if (valid){
      int o = b*PRE + i;
      bb = make_float4(tb[o], tb[NB*PRE+o], tb[2*NB*PRE+o], tb[3*NB*PRE+o]);
      ar = tb[4*NB*PRE+o];
    } else {
      diagn[(size_t)b*CH + il] = 0ULL;
    }
    uint64_t* Mr = Mnext + (((size_t)b*CH) + (size_t)il)*NW;
    int w0 = il >> 6;
    int jmax = PRE - base;
    constexpr int NWIN = CH/2048;
    for (int win=0; win<NWIN; win++){
      __syncthreads();                          // guards sbx reuse
      for (int s = t; s < 2048; s += 256){
        int j = base + win*2048 + s;
        if (j < PRE){
          int o = b*PRE + j;
          sbx[s] = make_float4(tb[o], tb[NB*PRE+o], tb[2*NB*PRE+o], tb[3*NB*PRE+o]);
          sar[s] = tb[4*NB*PRE+o];
        } else { sbx[s] = make_float4(0.f,0.f,-10.f,-10.f); sar[s] = 1.f; }
      }
      __syncthreads();
      int wlo = win*(2048/64), whi = wlo + (2048/64);
      if (!valid){
        for (int w=wlo; w<whi; w++) Mr[w] = 0;
        continue;
      }
      for (int w=wlo; w<whi; w++){
        if (w < w0){ Mr[w] = 0; continue; }
        uint64_t bits = 0;
        int jb = (w<<6) - win*2048;
        #pragma unroll 8
        for (int q=0; q<64; q++){
          int jl = jb + q;
          float4 cb = sbx[jl];
          bool ss = ((w<<6)+q < jmax) && iou_gt(bb.x,bb.y,bb.z,bb.w,ar, cb.x,cb.y,cb.z,cb.w,sar[jl]);
          bits |= ((uint64_t)ss) << q;
        }
        Mr[w] = bits;
        if (w == w0) diagn[(size_t)b*CH + il] = bits;
      }
    }
  }
}

template<int CH>
static void run_nms(uint64_t* M0, uint64_t* D0, uint64_t* M1, uint64_t* D1,
                    uint64_t* pres, uint32_t* keep, uint32_t* meta,
                    const float* tb, float* kbox, float* out, hipStream_t stream){
  constexpr int NPH   = (PRE + CH - 1)/CH;
  constexpr int UNITS = CH/256;
  // prologue: intra for phase 0 only (presup_0 zeroed by prep_k = all-valid)
  fused_k<CH><<<NB*UNITS, 256, 0, stream>>>(M1, D1, M0, D0, pres, keep, meta, tb, kbox, out, 0, 0, 0, 0);
  for (int p=0; p<NPH; p++){
    uint64_t* Mcur = (p&1) ? M1 : M0;
    uint64_t* Dcur = (p&1) ? D1 : D0;
    uint64_t* Mnxt = (p&1) ? M0 : M1;
    uint64_t* Dnxt = (p&1) ? D0 : D1;
    int nblk = (p < NPH-1) ? (16 + NB*UNITS) : 16;
    fused_k<CH><<<nblk, 256, 0, stream>>>(Mcur, Dcur, Mnxt, Dnxt, pres, keep, meta, tb, kbox, out,
                                          p*CH, (p+1)*CH, 16, (p==NPH-1) ? 1 : 0);
    if (p < NPH-1)
      cross2_k<CH><<<dim3(CH/256, 8, NB), 256, 0, stream>>>(tb, kbox, meta, pres, (p+1)*CH);
  }
}

extern "C" void kernel_launch(void* const* d_in, const int* in_sizes, int n_in,
                              void* d_out, int out_size, void* d_ws, size_t ws_size,
                              hipStream_t stream){
  (void)in_sizes; (void)n_in; (void)out_size;
  const float* scores = (const float*)d_in[0];
  const float* deltas = (const float*)d_in[1];
  const float* iminfo = (const float*)d_in[2];
  float* out = (float*)d_out;
  char* ws = (char*)d_ws;

  uint32_t* hist  = (uint32_t*)(ws + OFF_HIST);
  uint32_t* meta  = (uint32_t*)(ws + OFF_META);
  uint64_t* cand  = (uint64_t*)(ws + OFF_CAND);
  float*    tb    = (float*)   (ws + OFF_TB);
  uint32_t* keep  = (uint32_t*)(ws + OFF_KEEP);
  uint64_t* pres  = (uint64_t*)(ws + OFF_PRES);

  hipMemsetAsync(ws + OFF_HIST, 0, SZ_HIST + SZ_META, stream);
  hipMemsetAsync(ws + OFF_CAND, 0xFF, SZ_CAND, stream);

  prep_k    <<<(NB*NTOT+255)/256, 256, 0, stream>>>(scores, hist, pres);
  scanhist_k<<<NB, 1024, 0, stream>>>(hist, meta);
  gather_k  <<<NB*NTOT/256, 256, 0, stream>>>(scores, meta, cand);

  bsort_local_k<<<NB*8, 256, 0, stream>>>(cand);
  bsort_gfin_k <<<NB, 1024, 0, stream>>>(cand, deltas, iminfo, tb);

  {
    const size_t szd4 = (size_t)NB*4096*8;             // 524,288
    const size_t szm4 = (size_t)NB*4096*(4096/64)*8;   // 33,554,432
    const size_t need4 = (size_t)OFF_M + 2*szd4 + 2*szm4 + SZ_KBOX;
    if (ws_size >= need4){
      uint64_t* D0   = (uint64_t*)(ws + OFF_M);
      uint64_t* D1   = (uint64_t*)(ws + OFF_M + szd4);
      uint64_t* M0   = (uint64_t*)(ws + OFF_M + 2*szd4);
      uint64_t* M1   = (uint64_t*)(ws + OFF_M + 2*szd4 + szm4);
      float*    kbox = (float*)   (ws + OFF_M + 2*szd4 + 2*szm4);
      run_nms<4096>(M0, D0, M1, D1, pres, keep, meta, tb, kbox, out, stream);
    } else {
      const size_t szd2 = (size_t)NB*2048*8;           // 262,144
      const size_t szm2 = (size_t)NB*2048*(2048/64)*8; // 8,388,608
      uint64_t* D0   = (uint64_t*)(ws + OFF_M);
      uint64_t* D1   = (uint64_t*)(ws + OFF_M + szd2);
      uint64_t* M0   = (uint64_t*)(ws + OFF_M + 2*szd2);
      uint64_t* M1   = (uint64_t*)(ws + OFF_M + 2*szd2 + szm2);
      float*    kbox = (float*)   (ws + OFF_M + 2*szd2 + 2*szm2);
      run_nms<2048>(M0, D0, M1, D1, pres, keep, meta, tb, kbox, out, stream);
    }
  }
}

// Round 21
// 1599.844 us; speedup vs baseline: 1.3269x; 1.3269x over previous
//
#include <hip/hip_runtime.h>
#include <stdint.h>
#include <math.h>

#define NB   16
#define HF   128
#define WF   128
#define NA   9
#define HW   (HF*WF)          // 16384
#define NTOT (HW*NA)          // 147456
#define PRE  12000
#define POST 2000
#define CAP  16384

// fixed ws offsets (bytes); diag + M planes follow, sized by CHUNK at runtime
#define OFF_HIST  0u
#define SZ_HIST   (NB*65536u*4u)            // 4,194,304
#define OFF_META  (OFF_HIST + SZ_HIST)
#define SZ_META   4096u   // words: [0..15] cutoff | [32..47] nk | [256+b*16] gather count
#define OFF_CAND  (OFF_META + SZ_META)
#define SZ_CAND   (NB*CAP*8u)               // 2,097,152
#define OFF_TB    (OFF_CAND + SZ_CAND)
#define SZ_TB     (5u*NB*PRE*4u)            // 3,840,000
#define OFF_KEEP  (OFF_TB + SZ_TB)
#define SZ_KEEP   (NB*POST*4u)              // 128,000
#define OFF_PRES  (OFF_KEEP + SZ_KEEP)
#define SZ_PRES   (NB*64u*8u)               // 8,192 (max NW=64)
#define OFF_M     (OFF_PRES + SZ_PRES)      // = 10,271,744 (16B aligned)
#define SZ_KBOX   (5u*NB*POST*4u)           // 640,000

#define M_CNT(b)  (256 + (b)*16)

// base anchors = classic py-faster-rcnn table minus 1 (base [0,0,15,15]); a8.y2=359.
__constant__ float c_ax1[NA] = {-84.f,-176.f,-360.f,-56.f,-120.f,-248.f,-36.f,-80.f,-168.f};
__constant__ float c_ay1[NA] = {-40.f,-88.f,-184.f,-56.f,-120.f,-248.f,-80.f,-168.f,-344.f};
__constant__ float c_ax2[NA] = { 99.f, 191.f, 375.f, 71.f, 135.f, 263.f, 51.f, 95.f, 183.f};
__constant__ float c_ay2[NA] = { 55.f, 103.f, 199.f, 71.f, 135.f, 263.f, 95.f, 183.f, 359.f};

__device__ __forceinline__ uint32_t score_key(float f){
  uint32_t b = __float_as_uint(f);
  uint32_t u = (b & 0x80000000u) ? ~b : (b | 0x80000000u);
  return ~u;
}

__device__ __forceinline__ bool iou_gt(float ax1,float ay1,float ax2,float ay2,float aa,
                                       float bx1,float by1,float bx2,float by2,float ba){
  float xx1 = fmaxf(ax1,bx1);
  float yy1 = fmaxf(ay1,by1);
  float xx2 = fminf(ax2,bx2);
  float yy2 = fminf(ay2,by2);
  float w = fmaxf(__fadd_rn(__fsub_rn(xx2,xx1),1.0f), 0.0f);
  float h = fmaxf(__fadd_rn(__fsub_rn(yy2,yy1),1.0f), 0.0f);
  float inter = __fmul_rn(w,h);
  float denom = __fsub_rn(__fadd_rn(aa,ba), inter);
  float iou   = __fdiv_rn(inter, denom);
  return iou > 0.7f;
}

// -------- pass 1: histogram (+ zero presup) --------
__global__ void prep_k(const float* __restrict__ scores, uint32_t* __restrict__ hist,
                       uint64_t* __restrict__ presup){
  if (blockIdx.x == 0 && threadIdx.x < 256){
    #pragma unroll
    for (int k=0;k<4;k++) presup[threadIdx.x*4+k] = 0ULL;
  }
  int g = blockIdx.x*256 + threadIdx.x;
  if (g >= NB*NTOT) return;
  int hw = g & (HW-1);
  int t  = g >> 14;
  int ch = t % NA;
  int b  = t / NA;
  float s = scores[((size_t)(b*2*NA + NA + ch) << 14) + hw];
  uint32_t k = score_key(s);
  atomicAdd(&hist[((uint32_t)b<<16) + (k>>16)], 1u);
}

// -------- pass 2: cutoff --------
__global__ __launch_bounds__(1024) void scanhist_k(const uint32_t* __restrict__ hist,
                                                   uint32_t* __restrict__ meta){
  int b = blockIdx.x, t = threadIdx.x;
  const uint32_t* hh = hist + ((uint32_t)b<<16);
  int base = t<<6;
  uint32_t s=0;
  for (int i=0;i<64;i++) s += hh[base+i];
  __shared__ uint32_t part[1024];
  part[t]=s; __syncthreads();
  for (int off=1; off<1024; off<<=1){
    uint32_t v = (t>=off)? part[t-off] : 0u;
    __syncthreads();
    part[t] += v;
    __syncthreads();
  }
  uint32_t incl = part[t], excl = incl - s;
  if (excl < PRE && incl >= PRE){
    uint32_t run = excl;
    for (int i=0;i<64;i++){
      run += hh[base+i];
      if (run >= PRE){ meta[b] = (uint32_t)(base+i); break; }
    }
  }
}

// -------- pass 3: gather (block-aggregated atomics) --------
__global__ __launch_bounds__(256) void gather_k(const float* __restrict__ scores,
                                                uint32_t* __restrict__ meta,
                                                uint64_t* __restrict__ cand){
  int g = blockIdx.x*256 + threadIdx.x;
  int hw = g & (HW-1);
  int t  = g >> 14;
  int ch = t % NA;
  int b  = t / NA;
  float s = scores[((size_t)(b*2*NA + NA + ch) << 14) + hw];
  uint32_t k = score_key(s);
  bool sel = (k>>16) <= meta[b];
  unsigned long long m = __ballot(sel);
  int wid  = threadIdx.x >> 6;
  int lane = threadIdx.x & 63;
  __shared__ uint32_t woff[4];
  __shared__ uint32_t sbase;
  if (lane==0) woff[wid] = __popcll(m);
  __syncthreads();
  if (threadIdx.x==0){
    uint32_t a=0;
    #pragma unroll
    for (int i=0;i<4;i++){ uint32_t c=woff[i]; woff[i]=a; a+=c; }
    sbase = a ? atomicAdd(&meta[M_CNT(b)], a) : 0u;
  }
  __syncthreads();
  if (sel){
    uint32_t pos = sbase + woff[wid] + (uint32_t)__popcll(m & ((1ULL<<lane)-1ULL));
    if (pos < CAP){
      uint32_t idx = (uint32_t)hw*NA + (uint32_t)ch;
      cand[((size_t)b<<14) + pos] = ((uint64_t)k << 18) | (uint64_t)idx;
    }
  }
}

// ======== pass 4a: per-2048-chunk LDS bitonic sort (k=2..2048) ========
__global__ __launch_bounds__(256) void bsort_local_k(uint64_t* __restrict__ buf){
  __shared__ uint64_t S[2048];
  int blk = blockIdx.x;
  int b = blk>>3, chunk = blk&7;
  uint64_t* A_ = buf + ((size_t)b<<14) + ((size_t)chunk<<11);
  int t = threadIdx.x;
  int gbase = chunk<<11;
  for (int i=t;i<2048;i+=256) S[i]=A_[i];
  __syncthreads();
  for (unsigned k=2;k<=2048u;k<<=1){
    for (unsigned j=k>>1;j>0;j>>=1){
      for (int i=t;i<2048;i+=256){
        int l = i ^ (int)j;
        if (l > i){
          bool asc = (((gbase+i) & (int)k)==0);
          uint64_t a=S[i], c=S[l];
          bool sw = asc ? (a>c) : (a<c);
          if (sw){ S[i]=c; S[l]=a; }
        }
      }
      __syncthreads();
    }
  }
  for (int i=t;i<2048;i+=256) A_[i]=S[i];
}

// ======== pass 4b: finish sort (k=4096..16384) + inline extract (1 block/batch) ========
__global__ __launch_bounds__(1024) void bsort_gfin_k(uint64_t* __restrict__ buf,
                                                     const float* __restrict__ deltas,
                                                     const float* __restrict__ iminfo,
                                                     float* __restrict__ tb){
  __shared__ uint64_t S[2048];
  int b = blockIdx.x;
  uint64_t* A_ = buf + ((size_t)b<<14);
  int t = threadIdx.x;
  for (int k = 4096; k <= 16384; k <<= 1){
    for (int j = k>>1; j >= 2048; j >>= 1){
      for (int q = t; q < 8192; q += 1024){
        int i = ((q & ~(j-1))<<1) | (q & (j-1));
        int l = i + j;
        uint64_t a = A_[i], c = A_[l];
        bool asc = ((i & k)==0);
        if (asc ? (a>c) : (a<c)){ A_[i]=c; A_[l]=a; }
      }
      __syncthreads();
    }
    for (int c0 = 0; c0 < 8; c0++){
      uint64_t* C_ = A_ + (c0<<11);
      S[t] = C_[t]; S[t+1024] = C_[t+1024];
      __syncthreads();
      bool asc = (((c0<<11) & k)==0);
      for (int j = 1024; j >= 1; j >>= 1){
        int i = ((t & ~(j-1))<<1) | (t & (j-1));
        int l = i + j;
        uint64_t a=S[i], c=S[l];
        if (asc ? (a>c) : (a<c)){ S[i]=c; S[l]=a; }
        __syncthreads();
      }
      C_[t] = S[t]; C_[t+1024] = S[t+1024];
      __syncthreads();
    }
  }
  float maxx = __fsub_rn(iminfo[b*3+1],1.f);
  float maxy = __fsub_rn(iminfo[b*3+0],1.f);
  for (int j = t; j < PRE; j += 1024){
    uint64_t K = A_[j];
    uint32_t idx = (uint32_t)K & 0x3FFFFu;
    int ch = (int)(idx % NA);
    int hw = (int)(idx / NA);
    int w  = hw & (WF-1);
    int h  = hw >> 7;
    float sx = (float)(w*16), sy = (float)(h*16);
    float ax1 = c_ax1[ch]+sx, ay1 = c_ay1[ch]+sy, ax2 = c_ax2[ch]+sx, ay2 = c_ay2[ch]+sy;
    const float* dp = deltas + ((size_t)(b*4*NA + ch*4) << 14) + hw;
    float dx = dp[0], dy = dp[HW], dwv = dp[2*HW], dhv = dp[3*HW];
    float aw  = __fadd_rn(__fsub_rn(ax2,ax1),1.f);
    float ah  = __fadd_rn(__fsub_rn(ay2,ay1),1.f);
    float acx = __fadd_rn(ax1, __fmul_rn(0.5f,aw));
    float acy = __fadd_rn(ay1, __fmul_rn(0.5f,ah));
    float pcx = __fadd_rn(__fmul_rn(dx,aw), acx);
    float pcy = __fadd_rn(__fmul_rn(dy,ah), acy);
    float ew  = (float)exp((double)dwv);
    float eh  = (float)exp((double)dhv);
    float pw  = __fmul_rn(ew, aw);
    float ph  = __fmul_rn(eh, ah);
    float hx  = __fmul_rn(0.5f,pw), hy = __fmul_rn(0.5f,ph);
    float x1 = __fsub_rn(pcx,hx), y1 = __fsub_rn(pcy,hy);
    float x2 = __fadd_rn(pcx,hx), y2 = __fadd_rn(pcy,hy);
    x1 = fminf(fmaxf(x1,0.f),maxx); y1 = fminf(fmaxf(y1,0.f),maxy);
    x2 = fminf(fmaxf(x2,0.f),maxx); y2 = fminf(fmaxf(y2,0.f),maxy);
    float area = __fmul_rn(__fadd_rn(__fsub_rn(x2,x1),1.f), __fadd_rn(__fsub_rn(y2,y1),1.f));
    int o = b*PRE + j;
    tb[o]            = x1;
    tb[NB*PRE + o]   = y1;
    tb[2*NB*PRE + o] = x2;
    tb[3*NB*PRE + o] = y2;
    tb[4*NB*PRE + o] = area;
  }
}

// -------- NMS phase a: 2D-tiled cross (cand-tile x keep-tile), atomicOr merge --------
template<int CH>
__global__ __launch_bounds__(256) void cross2_k(const float* __restrict__ tb,
                                                const float* __restrict__ kbox,
                                                const uint32_t* __restrict__ meta,
                                                uint64_t* __restrict__ presup,
                                                int base){
  constexpr int NW = CH/64;
  int b  = blockIdx.z;
  int nk = (int)meta[32+b];
  int kt = blockIdx.y*256;
  if (kt >= nk) return;
  __shared__ float kx1[256],ky1[256],kx2[256],ky2[256],kar[256];
  int tt = threadIdx.x;
  int kk = kt + tt;
  if (kk < nk){
    int o = b*POST + kk;
    kx1[tt]=kbox[o];
    ky1[tt]=kbox[NB*POST+o];
    kx2[tt]=kbox[2*NB*POST+o];
    ky2[tt]=kbox[3*NB*POST+o];
    kar[tt]=kbox[4*NB*POST+o];
  }
  __syncthreads();
  int jl = blockIdx.x*256 + tt;
  int j  = base + jl;
  bool supp = false;
  if (j < PRE){
    int o = b*PRE + j;
    float x1=tb[o], y1=tb[NB*PRE+o], x2=tb[2*NB*PRE+o], y2=tb[3*NB*PRE+o], ar=tb[4*NB*PRE+o];
    int lim = min(256, nk-kt);
    for (int q=0;q<lim;q++){
      if (iou_gt(kx1[q],ky1[q],kx2[q],ky2[q],kar[q], x1,y1,x2,y2,ar)){ supp=true; break; }
    }
  }
  unsigned long long m = __ballot(supp);
  if ((tt & 63)==0 && m)
    atomicOr((unsigned long long*)&presup[b*NW + (jl>>6)], m);
}

// -------- fused: scan(phase p, diag-sidecar) ∥ intra(phase p+1, window-split) --------
template<int CH>
__global__ __launch_bounds__(256) void fused_k(const uint64_t* __restrict__ Mscan,
                                               const uint64_t* __restrict__ diagc,
                                               uint64_t* __restrict__ Mnext,
                                               uint64_t* __restrict__ diagn,
                                               uint64_t* __restrict__ presup,
                                               uint32_t* __restrict__ keep,
                                               uint32_t* __restrict__ meta,
                                               const float* __restrict__ tb,
                                               float* __restrict__ kbox,
                                               float* __restrict__ outp,
                                               int base_scan, int base_next, int nscan,
                                               int dofinal){
  constexpr int NW    = CH/64;     // words per row
  constexpr int UNITS = CH/256;    // row-groups per batch
  constexpr int WCOLS = 1024;      // cols per intra window block
  constexpr int NWIN  = CH/WCOLS;  // windows per chunk
  constexpr int WPW   = WCOLS/64;  // words per window (16)
  __shared__ __align__(16) char smem[40960];
  __shared__ int s_nk;
  int t = threadIdx.x;

  if ((int)blockIdx.x < nscan){
    // ===== scan role: diag-sidecar keep chain (bit-identical decisions) =====
    uint64_t* sdiag = (uint64_t*)smem;         // CH*8 bytes (<=32KB)
    int b = blockIdx.x;
    int l = t & 63, wv = t >> 6;
    const uint64_t* Mb = Mscan + (size_t)b*CH*NW;
    for (int i=t; i<CH; i+=256) sdiag[i] = diagc[(size_t)b*CH + i];
    __syncthreads();
    int nk0 = (int)meta[32+b];
    int nk = nk0;
    if (wv==0){
      uint64_t acc = (l<NW) ? presup[b*NW + l] : ~0ULL;
      for (int w=0; w<NW; w++){
        if (nk >= POST) break;
        uint64_t tile = sdiag[(w<<6) + l];     // lane l: diag word of row w*64+l
        uint64_t cur  = __shfl(acc, w);
        uint64_t kmask = 0;
        while (cur != ~0ULL && nk < POST){
          int p = __ffsll((unsigned long long)(~cur)) - 1;
          if (l==0) keep[b*POST+nk] = (uint32_t)(base_scan + (w<<6) + p);
          nk++;
          kmask |= (1ULL<<p);
          cur |= (1ULL<<p) | (uint64_t)__shfl(tile, p);
        }
        while (kmask){
          int ps[16];
          #pragma unroll
          for (int i2=0;i2<16;i2++){
            if (kmask){ ps[i2] = __ffsll((unsigned long long)kmask)-1; kmask &= kmask-1ULL; }
            else ps[i2] = -1;
          }
          uint64_t r = 0;
          #pragma unroll
          for (int i2=0;i2<16;i2++){
            uint64_t v = (ps[i2]>=0 && l<NW) ? Mb[(size_t)((w<<6)+ps[i2])*NW + l] : 0ULL;
            r |= v;
          }
          acc |= r;
        }
      }
      if (l==0){ meta[32+b] = (uint32_t)nk; s_nk = nk; }
      if (l<NW){
        long rem = (long)PRE - (long)(base_next + (l<<6));
        uint64_t v = (rem >= 64) ? 0ULL : ((rem <= 0) ? ~0ULL : ~((1ULL<<rem) - 1ULL));
        presup[b*NW + l] = v;
      }
    }
    __syncthreads();
    int nkf = s_nk;
    for (int i = nk0 + t; i < nkf; i += 256){
      int j = (int)keep[b*POST+i];
      int o = b*PRE + j;
      int d = b*POST + i;
      kbox[d]            = tb[o];
      kbox[NB*POST + d]  = tb[NB*PRE+o];
      kbox[2*NB*POST + d]= tb[2*NB*PRE+o];
      kbox[3*NB*POST + d]= tb[3*NB*PRE+o];
      kbox[4*NB*POST + d]= tb[4*NB*PRE+o];
    }
    if (dofinal){
      for (int i = t; i < POST; i += 256){
        float x1=0.f,y1=0.f,x2=0.f,y2=0.f;
        if (i < nkf){
          int j = (int)keep[b*POST+i];
          int o = b*PRE + j;
          x1=tb[o]; y1=tb[NB*PRE+o]; x2=tb[2*NB*PRE+o]; y2=tb[3*NB*PRE+o];
        }
        float* op = outp + (size_t)(b*POST+i)*5;
        op[0]=(float)b; op[1]=x1; op[2]=y1; op[3]=x2; op[4]=y2;
      }
    }
  } else {
    // ===== intra role: window-split bit-matrix for phase p+1 =====
    float4* sbx = (float4*)smem;               // 16 KB (1024 col boxes)
    float*  sar = (float*)(smem + 16384);      // 4 KB
    int bid = (int)blockIdx.x - nscan;         // in [0, NB*UNITS*NWIN)
    int b   = bid / (UNITS*NWIN);
    int rem = bid % (UNITS*NWIN);
    int rg  = rem / NWIN;
    int win = rem % NWIN;
    int il  = rg*256 + t;
    int base = base_next;
    int i = base + il;
    bool valid = (i < PRE);
    float4 bb = make_float4(0.f,0.f,0.f,0.f);
    float  ar = 1.f;
    if (valid){
      int o = b*PRE + i;
      bb = make_float4(tb[o], tb[NB*PRE+o], tb[2*NB*PRE+o], tb[3*NB*PRE+o]);
      ar = tb[4*NB*PRE+o];
    }
    // stage this window's columns
    for (int s = t; s < WCOLS; s += 256){
      int j = base + win*WCOLS + s;
      if (j < PRE){
        int o = b*PRE + j;
        sbx[s] = make_float4(tb[o], tb[NB*PRE+o], tb[2*NB*PRE+o], tb[3*NB*PRE+o]);
        sar[s] = tb[4*NB*PRE+o];
      } else { sbx[s] = make_float4(0.f,0.f,-10.f,-10.f); sar[s] = 1.f; }
    }
    __syncthreads();
    uint64_t* Mr = Mnext + (((size_t)b*CH) + (size_t)il)*NW;
    int w0 = il >> 6;
    int jmax = PRE - base;
    int wlo = win*WPW, whi = wlo + WPW;
    if (!valid){
      for (int w=wlo; w<whi; w++) Mr[w] = 0;
      if (win == 0) diagn[(size_t)b*CH + il] = 0ULL;
      return;
    }
    for (int w=wlo; w<whi; w++){
      if (w < w0){ Mr[w] = 0; continue; }
      uint64_t bits = 0;
      int jb = (w<<6) - win*WCOLS;
      #pragma unroll 8
      for (int q=0; q<64; q++){
        int jl = jb + q;
        float4 cb = sbx[jl];
        bool ss = ((w<<6)+q < jmax) && iou_gt(bb.x,bb.y,bb.z,bb.w,ar, cb.x,cb.y,cb.z,cb.w,sar[jl]);
        bits |= ((uint64_t)ss) << q;
      }
      Mr[w] = bits;
      if (w == w0) diagn[(size_t)b*CH + il] = bits;
    }
  }
}

template<int CH>
static void run_nms(uint64_t* M0, uint64_t* D0, uint64_t* M1, uint64_t* D1,
                    uint64_t* pres, uint32_t* keep, uint32_t* meta,
                    const float* tb, float* kbox, float* out, hipStream_t stream){
  constexpr int NPH   = (PRE + CH - 1)/CH;
  constexpr int UNITS = CH/256;
  constexpr int NWIN  = CH/1024;
  constexpr int INTRA = NB*UNITS*NWIN;
  // prologue: intra for phase 0 only (presup_0 zeroed by prep_k = all-valid)
  fused_k<CH><<<INTRA, 256, 0, stream>>>(M1, D1, M0, D0, pres, keep, meta, tb, kbox, out, 0, 0, 0, 0);
  for (int p=0; p<NPH; p++){
    uint64_t* Mcur = (p&1) ? M1 : M0;
    uint64_t* Dcur = (p&1) ? D1 : D0;
    uint64_t* Mnxt = (p&1) ? M0 : M1;
    uint64_t* Dnxt = (p&1) ? D0 : D1;
    int nblk = (p < NPH-1) ? (16 + INTRA) : 16;
    fused_k<CH><<<nblk, 256, 0, stream>>>(Mcur, Dcur, Mnxt, Dnxt, pres, keep, meta, tb, kbox, out,
                                          p*CH, (p+1)*CH, 16, (p==NPH-1) ? 1 : 0);
    if (p < NPH-1)
      cross2_k<CH><<<dim3(CH/256, 8, NB), 256, 0, stream>>>(tb, kbox, meta, pres, (p+1)*CH);
  }
}

extern "C" void kernel_launch(void* const* d_in, const int* in_sizes, int n_in,
                              void* d_out, int out_size, void* d_ws, size_t ws_size,
                              hipStream_t stream){
  (void)in_sizes; (void)n_in; (void)out_size;
  const float* scores = (const float*)d_in[0];
  const float* deltas = (const float*)d_in[1];
  const float* iminfo = (const float*)d_in[2];
  float* out = (float*)d_out;
  char* ws = (char*)d_ws;

  uint32_t* hist  = (uint32_t*)(ws + OFF_HIST);
  uint32_t* meta  = (uint32_t*)(ws + OFF_META);
  uint64_t* cand  = (uint64_t*)(ws + OFF_CAND);
  float*    tb    = (float*)   (ws + OFF_TB);
  uint32_t* keep  = (uint32_t*)(ws + OFF_KEEP);
  uint64_t* pres  = (uint64_t*)(ws + OFF_PRES);

  hipMemsetAsync(ws + OFF_HIST, 0, SZ_HIST + SZ_META, stream);
  hipMemsetAsync(ws + OFF_CAND, 0xFF, SZ_CAND, stream);

  prep_k    <<<(NB*NTOT+255)/256, 256, 0, stream>>>(scores, hist, pres);
  scanhist_k<<<NB, 1024, 0, stream>>>(hist, meta);
  gather_k  <<<NB*NTOT/256, 256, 0, stream>>>(scores, meta, cand);

  bsort_local_k<<<NB*8, 256, 0, stream>>>(cand);
  bsort_gfin_k <<<NB, 1024, 0, stream>>>(cand, deltas, iminfo, tb);

  {
    const size_t szd4 = (size_t)NB*4096*8;             // 524,288
    const size_t szm4 = (size_t)NB*4096*(4096/64)*8;   // 33,554,432
    const size_t need4 = (size_t)OFF_M + 2*szd4 + 2*szm4 + SZ_KBOX;
    if (ws_size >= need4){
      uint64_t* D0   = (uint64_t*)(ws + OFF_M);
      uint64_t* D1   = (uint64_t*)(ws + OFF_M + szd4);
      uint64_t* M0   = (uint64_t*)(ws + OFF_M + 2*szd4);
      uint64_t* M1   = (uint64_t*)(ws + OFF_M + 2*szd4 + szm4);
      float*    kbox = (float*)   (ws + OFF_M + 2*szd4 + 2*szm4);
      run_nms<4096>(M0, D0, M1, D1, pres, keep, meta, tb, kbox, out, stream);
    } else {
      const size_t szd2 = (size_t)NB*2048*8;           // 262,144
      const size_t szm2 = (size_t)NB*2048*(2048/64)*8; // 8,388,608
      uint64_t* D0   = (uint64_t*)(ws + OFF_M);
      uint64_t* D1   = (uint64_t*)(ws + OFF_M + szd2);
      uint64_t* M0   = (uint64_t*)(ws + OFF_M + 2*szd2);
      uint64_t* M1   = (uint64_t*)(ws + OFF_M + 2*szd2 + szm2);
      float*    kbox = (float*)   (ws + OFF_M + 2*szd2 + 2*szm2);
      run_nms<2048>(M0, D0, M1, D1, pres, keep, meta, tb, kbox, out, stream);
    }
  }
}

// Round 22
// 1541.723 us; speedup vs baseline: 1.3769x; 1.0377x over previous
//
#include <hip/hip_runtime.h>
#include <stdint.h>
#include <math.h>

#define NB   16
#define HF   128
#define WF   128
#define NA   9
#define HW   (HF*WF)          // 16384
#define NTOT (HW*NA)          // 147456
#define PRE  12000
#define POST 2000
#define CAP  16384

// fixed ws offsets (bytes); diag + M planes follow, sized by CHUNK at runtime
#define OFF_HIST  0u
#define SZ_HIST   (NB*65536u*4u)            // 4,194,304
#define OFF_META  (OFF_HIST + SZ_HIST)
#define SZ_META   4096u   // words: [0..15] cutoff | [32..47] nk | [256+b*16] gather count
#define OFF_CAND  (OFF_META + SZ_META)
#define SZ_CAND   (NB*CAP*8u)               // 2,097,152
#define OFF_TB    (OFF_CAND + SZ_CAND)
#define SZ_TB     (5u*NB*PRE*4u)            // 3,840,000
#define OFF_KEEP  (OFF_TB + SZ_TB)
#define SZ_KEEP   (NB*POST*4u)              // 128,000
#define OFF_PRES  (OFF_KEEP + SZ_KEEP)
#define SZ_PRES   (NB*64u*8u)               // 8,192 (max NW=64)
#define OFF_M     (OFF_PRES + SZ_PRES)      // = 10,271,744 (16B aligned)
#define SZ_KBOX   (5u*NB*POST*4u)           // 640,000

#define M_CNT(b)  (256 + (b)*16)

// base anchors = classic py-faster-rcnn table minus 1 (base [0,0,15,15]); a8.y2=359.
__constant__ float c_ax1[NA] = {-84.f,-176.f,-360.f,-56.f,-120.f,-248.f,-36.f,-80.f,-168.f};
__constant__ float c_ay1[NA] = {-40.f,-88.f,-184.f,-56.f,-120.f,-248.f,-80.f,-168.f,-344.f};
__constant__ float c_ax2[NA] = { 99.f, 191.f, 375.f, 71.f, 135.f, 263.f, 51.f, 95.f, 183.f};
__constant__ float c_ay2[NA] = { 55.f, 103.f, 199.f, 71.f, 135.f, 263.f, 95.f, 183.f, 359.f};

__device__ __forceinline__ uint32_t score_key(float f){
  uint32_t b = __float_as_uint(f);
  uint32_t u = (b & 0x80000000u) ? ~b : (b | 0x80000000u);
  return ~u;
}

__device__ __forceinline__ bool iou_gt(float ax1,float ay1,float ax2,float ay2,float aa,
                                       float bx1,float by1,float bx2,float by2,float ba){
  float xx1 = fmaxf(ax1,bx1);
  float yy1 = fmaxf(ay1,by1);
  float xx2 = fminf(ax2,bx2);
  float yy2 = fminf(ay2,by2);
  float w = fmaxf(__fadd_rn(__fsub_rn(xx2,xx1),1.0f), 0.0f);
  float h = fmaxf(__fadd_rn(__fsub_rn(yy2,yy1),1.0f), 0.0f);
  float inter = __fmul_rn(w,h);
  float denom = __fsub_rn(__fadd_rn(aa,ba), inter);
  float iou   = __fdiv_rn(inter, denom);
  return iou > 0.7f;
}

// -------- pass 1: histogram (+ zero presup) --------
__global__ void prep_k(const float* __restrict__ scores, uint32_t* __restrict__ hist,
                       uint64_t* __restrict__ presup){
  if (blockIdx.x == 0 && threadIdx.x < 256){
    #pragma unroll
    for (int k=0;k<4;k++) presup[threadIdx.x*4+k] = 0ULL;
  }
  int g = blockIdx.x*256 + threadIdx.x;
  if (g >= NB*NTOT) return;
  int hw = g & (HW-1);
  int t  = g >> 14;
  int ch = t % NA;
  int b  = t / NA;
  float s = scores[((size_t)(b*2*NA + NA + ch) << 14) + hw];
  uint32_t k = score_key(s);
  atomicAdd(&hist[((uint32_t)b<<16) + (k>>16)], 1u);
}

// -------- pass 2: cutoff --------
__global__ __launch_bounds__(1024) void scanhist_k(const uint32_t* __restrict__ hist,
                                                   uint32_t* __restrict__ meta){
  int b = blockIdx.x, t = threadIdx.x;
  const uint32_t* hh = hist + ((uint32_t)b<<16);
  int base = t<<6;
  uint32_t s=0;
  for (int i=0;i<64;i++) s += hh[base+i];
  __shared__ uint32_t part[1024];
  part[t]=s; __syncthreads();
  for (int off=1; off<1024; off<<=1){
    uint32_t v = (t>=off)? part[t-off] : 0u;
    __syncthreads();
    part[t] += v;
    __syncthreads();
  }
  uint32_t incl = part[t], excl = incl - s;
  if (excl < PRE && incl >= PRE){
    uint32_t run = excl;
    for (int i=0;i<64;i++){
      run += hh[base+i];
      if (run >= PRE){ meta[b] = (uint32_t)(base+i); break; }
    }
  }
}

// -------- pass 3: gather (block-aggregated atomics) --------
__global__ __launch_bounds__(256) void gather_k(const float* __restrict__ scores,
                                                uint32_t* __restrict__ meta,
                                                uint64_t* __restrict__ cand){
  int g = blockIdx.x*256 + threadIdx.x;
  int hw = g & (HW-1);
  int t  = g >> 14;
  int ch = t % NA;
  int b  = t / NA;
  float s = scores[((size_t)(b*2*NA + NA + ch) << 14) + hw];
  uint32_t k = score_key(s);
  bool sel = (k>>16) <= meta[b];
  unsigned long long m = __ballot(sel);
  int wid  = threadIdx.x >> 6;
  int lane = threadIdx.x & 63;
  __shared__ uint32_t woff[4];
  __shared__ uint32_t sbase;
  if (lane==0) woff[wid] = __popcll(m);
  __syncthreads();
  if (threadIdx.x==0){
    uint32_t a=0;
    #pragma unroll
    for (int i=0;i<4;i++){ uint32_t c=woff[i]; woff[i]=a; a+=c; }
    sbase = a ? atomicAdd(&meta[M_CNT(b)], a) : 0u;
  }
  __syncthreads();
  if (sel){
    uint32_t pos = sbase + woff[wid] + (uint32_t)__popcll(m & ((1ULL<<lane)-1ULL));
    if (pos < CAP){
      uint32_t idx = (uint32_t)hw*NA + (uint32_t)ch;
      cand[((size_t)b<<14) + pos] = ((uint64_t)k << 18) | (uint64_t)idx;
    }
  }
}

// ======== pass 4a: per-2048-chunk LDS bitonic sort (k=2..2048) ========
__global__ __launch_bounds__(256) void bsort_local_k(uint64_t* __restrict__ buf){
  __shared__ uint64_t S[2048];
  int blk = blockIdx.x;
  int b = blk>>3, chunk = blk&7;
  uint64_t* A_ = buf + ((size_t)b<<14) + ((size_t)chunk<<11);
  int t = threadIdx.x;
  int gbase = chunk<<11;
  for (int i=t;i<2048;i+=256) S[i]=A_[i];
  __syncthreads();
  for (unsigned k=2;k<=2048u;k<<=1){
    for (unsigned j=k>>1;j>0;j>>=1){
      for (int i=t;i<2048;i+=256){
        int l = i ^ (int)j;
        if (l > i){
          bool asc = (((gbase+i) & (int)k)==0);
          uint64_t a=S[i], c=S[l];
          bool sw = asc ? (a>c) : (a<c);
          if (sw){ S[i]=c; S[l]=a; }
        }
      }
      __syncthreads();
    }
  }
  for (int i=t;i<2048;i+=256) A_[i]=S[i];
}

// ======== pass 4b: finish sort (k=4096..16384) + inline extract (1 block/batch) ========
__global__ __launch_bounds__(1024) void bsort_gfin_k(uint64_t* __restrict__ buf,
                                                     const float* __restrict__ deltas,
                                                     const float* __restrict__ iminfo,
                                                     float* __restrict__ tb){
  __shared__ uint64_t S[2048];
  int b = blockIdx.x;
  uint64_t* A_ = buf + ((size_t)b<<14);
  int t = threadIdx.x;
  for (int k = 4096; k <= 16384; k <<= 1){
    for (int j = k>>1; j >= 2048; j >>= 1){
      for (int q = t; q < 8192; q += 1024){
        int i = ((q & ~(j-1))<<1) | (q & (j-1));
        int l = i + j;
        uint64_t a = A_[i], c = A_[l];
        bool asc = ((i & k)==0);
        if (asc ? (a>c) : (a<c)){ A_[i]=c; A_[l]=a; }
      }
      __syncthreads();
    }
    for (int c0 = 0; c0 < 8; c0++){
      uint64_t* C_ = A_ + (c0<<11);
      S[t] = C_[t]; S[t+1024] = C_[t+1024];
      __syncthreads();
      bool asc = (((c0<<11) & k)==0);
      for (int j = 1024; j >= 1; j >>= 1){
        int i = ((t & ~(j-1))<<1) | (t & (j-1));
        int l = i + j;
        uint64_t a=S[i], c=S[l];
        if (asc ? (a>c) : (a<c)){ S[i]=c; S[l]=a; }
        __syncthreads();
      }
      C_[t] = S[t]; C_[t+1024] = S[t+1024];
      __syncthreads();
    }
  }
  float maxx = __fsub_rn(iminfo[b*3+1],1.f);
  float maxy = __fsub_rn(iminfo[b*3+0],1.f);
  for (int j = t; j < PRE; j += 1024){
    uint64_t K = A_[j];
    uint32_t idx = (uint32_t)K & 0x3FFFFu;
    int ch = (int)(idx % NA);
    int hw = (int)(idx / NA);
    int w  = hw & (WF-1);
    int h  = hw >> 7;
    float sx = (float)(w*16), sy = (float)(h*16);
    float ax1 = c_ax1[ch]+sx, ay1 = c_ay1[ch]+sy, ax2 = c_ax2[ch]+sx, ay2 = c_ay2[ch]+sy;
    const float* dp = deltas + ((size_t)(b*4*NA + ch*4) << 14) + hw;
    float dx = dp[0], dy = dp[HW], dwv = dp[2*HW], dhv = dp[3*HW];
    float aw  = __fadd_rn(__fsub_rn(ax2,ax1),1.f);
    float ah  = __fadd_rn(__fsub_rn(ay2,ay1),1.f);
    float acx = __fadd_rn(ax1, __fmul_rn(0.5f,aw));
    float acy = __fadd_rn(ay1, __fmul_rn(0.5f,ah));
    float pcx = __fadd_rn(__fmul_rn(dx,aw), acx);
    float pcy = __fadd_rn(__fmul_rn(dy,ah), acy);
    float ew  = (float)exp((double)dwv);
    float eh  = (float)exp((double)dhv);
    float pw  = __fmul_rn(ew, aw);
    float ph  = __fmul_rn(eh, ah);
    float hx  = __fmul_rn(0.5f,pw), hy = __fmul_rn(0.5f,ph);
    float x1 = __fsub_rn(pcx,hx), y1 = __fsub_rn(pcy,hy);
    float x2 = __fadd_rn(pcx,hx), y2 = __fadd_rn(pcy,hy);
    x1 = fminf(fmaxf(x1,0.f),maxx); y1 = fminf(fmaxf(y1,0.f),maxy);
    x2 = fminf(fmaxf(x2,0.f),maxx); y2 = fminf(fmaxf(y2,0.f),maxy);
    float area = __fmul_rn(__fadd_rn(__fsub_rn(x2,x1),1.f), __fadd_rn(__fsub_rn(y2,y1),1.f));
    int o = b*PRE + j;
    tb[o]            = x1;
    tb[NB*PRE + o]   = y1;
    tb[2*NB*PRE + o] = x2;
    tb[3*NB*PRE + o] = y2;
    tb[4*NB*PRE + o] = area;
  }
}

// -------- NMS phase a: 2D-tiled cross (cand-tile x keep-tile), atomicOr merge --------
template<int CH>
__global__ __launch_bounds__(256) void cross2_k(const float* __restrict__ tb,
                                                const float* __restrict__ kbox,
                                                const uint32_t* __restrict__ meta,
                                                uint64_t* __restrict__ presup,
                                                int base){
  constexpr int NW = CH/64;
  int b  = blockIdx.z;
  int nk = (int)meta[32+b];
  int kt = blockIdx.y*256;
  if (kt >= nk) return;
  __shared__ float kx1[256],ky1[256],kx2[256],ky2[256],kar[256];
  int tt = threadIdx.x;
  int kk = kt + tt;
  if (kk < nk){
    int o = b*POST + kk;
    kx1[tt]=kbox[o];
    ky1[tt]=kbox[NB*POST+o];
    kx2[tt]=kbox[2*NB*POST+o];
    ky2[tt]=kbox[3*NB*POST+o];
    kar[tt]=kbox[4*NB*POST+o];
  }
  __syncthreads();
  int jl = blockIdx.x*256 + tt;
  int j  = base + jl;
  bool supp = false;
  if (j < PRE){
    int o = b*PRE + j;
    float x1=tb[o], y1=tb[NB*PRE+o], x2=tb[2*NB*PRE+o], y2=tb[3*NB*PRE+o], ar=tb[4*NB*PRE+o];
    int lim = min(256, nk-kt);
    for (int q=0;q<lim;q++){
      if (iou_gt(kx1[q],ky1[q],kx2[q],ky2[q],kar[q], x1,y1,x2,y2,ar)){ supp=true; break; }
    }
  }
  unsigned long long m = __ballot(supp);
  if ((tt & 63)==0 && m)
    atomicOr((unsigned long long*)&presup[b*NW + (jl>>6)], m);
}

// -------- fused: scan(phase p, diag-sidecar) ∥ intra(phase p+1, 512-col windows,
//          upper-triangle-only M writes) --------
template<int CH>
__global__ __launch_bounds__(256) void fused_k(const uint64_t* __restrict__ Mscan,
                                               const uint64_t* __restrict__ diagc,
                                               uint64_t* __restrict__ Mnext,
                                               uint64_t* __restrict__ diagn,
                                               uint64_t* __restrict__ presup,
                                               uint32_t* __restrict__ keep,
                                               uint32_t* __restrict__ meta,
                                               const float* __restrict__ tb,
                                               float* __restrict__ kbox,
                                               float* __restrict__ outp,
                                               int base_scan, int base_next, int nscan,
                                               int dofinal){
  constexpr int NW    = CH/64;     // words per row
  constexpr int UNITS = CH/256;    // row-groups per batch
  constexpr int WCOLS = 512;       // cols per intra window block
  constexpr int NWIN  = CH/WCOLS;  // windows per chunk
  constexpr int WPW   = WCOLS/64;  // words per window (8)
  __shared__ __align__(16) char smem[40960];
  __shared__ int s_nk;
  int t = threadIdx.x;

  if ((int)blockIdx.x < nscan){
    // ===== scan role: diag-sidecar keep chain (bit-identical decisions) =====
    uint64_t* sdiag = (uint64_t*)smem;         // CH*8 bytes (<=32KB)
    int b = blockIdx.x;
    int l = t & 63, wv = t >> 6;
    const uint64_t* Mb = Mscan + (size_t)b*CH*NW;
    for (int i=t; i<CH; i+=256) sdiag[i] = diagc[(size_t)b*CH + i];
    __syncthreads();
    int nk0 = (int)meta[32+b];
    int nk = nk0;
    if (wv==0){
      uint64_t acc = (l<NW) ? presup[b*NW + l] : ~0ULL;
      for (int w=0; w<NW; w++){
        if (nk >= POST) break;
        uint64_t tile = sdiag[(w<<6) + l];     // lane l: diag word of row w*64+l
        uint64_t cur  = __shfl(acc, w);
        uint64_t kmask = 0;
        while (cur != ~0ULL && nk < POST){
          int p = __ffsll((unsigned long long)(~cur)) - 1;
          if (l==0) keep[b*POST+nk] = (uint32_t)(base_scan + (w<<6) + p);
          nk++;
          kmask |= (1ULL<<p);
          cur |= (1ULL<<p) | (uint64_t)__shfl(tile, p);
        }
        // batched row-OR (upper-triangle only: words l >= w exist)
        bool lok = (l < NW) && (l >= w);
        while (kmask){
          int ps[16];
          #pragma unroll
          for (int i2=0;i2<16;i2++){
            if (kmask){ ps[i2] = __ffsll((unsigned long long)kmask)-1; kmask &= kmask-1ULL; }
            else ps[i2] = -1;
          }
          uint64_t r = 0;
          #pragma unroll
          for (int i2=0;i2<16;i2++){
            uint64_t v = (ps[i2]>=0 && lok) ? Mb[(size_t)((w<<6)+ps[i2])*NW + l] : 0ULL;
            r |= v;
          }
          acc |= r;
        }
      }
      if (l==0){ meta[32+b] = (uint32_t)nk; s_nk = nk; }
      if (l<NW){
        long rem = (long)PRE - (long)(base_next + (l<<6));
        uint64_t v = (rem >= 64) ? 0ULL : ((rem <= 0) ? ~0ULL : ~((1ULL<<rem) - 1ULL));
        presup[b*NW + l] = v;
      }
    }
    __syncthreads();
    int nkf = s_nk;
    for (int i = nk0 + t; i < nkf; i += 256){
      int j = (int)keep[b*POST+i];
      int o = b*PRE + j;
      int d = b*POST + i;
      kbox[d]            = tb[o];
      kbox[NB*POST + d]  = tb[NB*PRE+o];
      kbox[2*NB*POST + d]= tb[2*NB*PRE+o];
      kbox[3*NB*POST + d]= tb[3*NB*PRE+o];
      kbox[4*NB*POST + d]= tb[4*NB*PRE+o];
    }
    if (dofinal){
      for (int i = t; i < POST; i += 256){
        float x1=0.f,y1=0.f,x2=0.f,y2=0.f;
        if (i < nkf){
          int j = (int)keep[b*POST+i];
          int o = b*PRE + j;
          x1=tb[o]; y1=tb[NB*PRE+o]; x2=tb[2*NB*PRE+o]; y2=tb[3*NB*PRE+o];
        }
        float* op = outp + (size_t)(b*POST+i)*5;
        op[0]=(float)b; op[1]=x1; op[2]=y1; op[3]=x2; op[4]=y2;
      }
    }
  } else {
    // ===== intra role: window-split bit-matrix, upper-triangle writes only =====
    float4* sbx = (float4*)smem;               // 8 KB (512 col boxes)
    float*  sar = (float*)(smem + 8192);       // 2 KB
    int bid = (int)blockIdx.x - nscan;         // in [0, NB*UNITS*NWIN)
    int b   = bid / (UNITS*NWIN);
    int rem = bid % (UNITS*NWIN);
    int rg  = rem / NWIN;
    int win = rem % NWIN;
    int il  = rg*256 + t;
    int base = base_next;
    int i = base + il;
    bool valid = (i < PRE);
    int w0 = il >> 6;
    int wlo = win*WPW, whi = wlo + WPW;
    if (!valid){
      if (win == 0) diagn[(size_t)b*CH + il] = 0ULL;   // M rows never read for invalid rows
      // still participate in staging barrier below? No: block-uniform path —
      // all threads in this block may mix valid/invalid; fall through.
    }
    // stage this window's columns
    for (int s = t; s < WCOLS; s += 256){
      int j = base + win*WCOLS + s;
      if (j < PRE){
        int o = b*PRE + j;
        sbx[s] = make_float4(tb[o], tb[NB*PRE+o], tb[2*NB*PRE+o], tb[3*NB*PRE+o]);
        sar[s] = tb[4*NB*PRE+o];
      } else { sbx[s] = make_float4(0.f,0.f,-10.f,-10.f); sar[s] = 1.f; }
    }
    __syncthreads();
    if (!valid || whi <= w0) return;           // nothing to write in this window
    float4 bb;
    float  ar;
    {
      int o = b*PRE + i;
      bb = make_float4(tb[o], tb[NB*PRE+o], tb[2*NB*PRE+o], tb[3*NB*PRE+o]);
      ar = tb[4*NB*PRE+o];
    }
    uint64_t* Mr = Mnext + (((size_t)b*CH) + (size_t)il)*NW;
    int jmax = PRE - base;
    int wstart = (w0 > wlo) ? w0 : wlo;
    for (int w=wstart; w<whi; w++){
      uint64_t bits = 0;
      int jb = (w<<6) - win*WCOLS;
      #pragma unroll 8
      for (int q=0; q<64; q++){
        int jl = jb + q;
        float4 cb = sbx[jl];
        bool ss = ((w<<6)+q < jmax) && iou_gt(bb.x,bb.y,bb.z,bb.w,ar, cb.x,cb.y,cb.z,cb.w,sar[jl]);
        bits |= ((uint64_t)ss) << q;
      }
      Mr[w] = bits;
      if (w == w0) diagn[(size_t)b*CH + il] = bits;
    }
  }
}

template<int CH>
static void run_nms(uint64_t* M0, uint64_t* D0, uint64_t* M1, uint64_t* D1,
                    uint64_t* pres, uint32_t* keep, uint32_t* meta,
                    const float* tb, float* kbox, float* out, hipStream_t stream){
  constexpr int NPH   = (PRE + CH - 1)/CH;
  constexpr int UNITS = CH/256;
  constexpr int NWIN  = CH/512;
  constexpr int INTRA = NB*UNITS*NWIN;
  // prologue: intra for phase 0 only (presup_0 zeroed by prep_k = all-valid)
  fused_k<CH><<<INTRA, 256, 0, stream>>>(M1, D1, M0, D0, pres, keep, meta, tb, kbox, out, 0, 0, 0, 0);
  for (int p=0; p<NPH; p++){
    uint64_t* Mcur = (p&1) ? M1 : M0;
    uint64_t* Dcur = (p&1) ? D1 : D0;
    uint64_t* Mnxt = (p&1) ? M0 : M1;
    uint64_t* Dnxt = (p&1) ? D0 : D1;
    int nblk = (p < NPH-1) ? (16 + INTRA) : 16;
    fused_k<CH><<<nblk, 256, 0, stream>>>(Mcur, Dcur, Mnxt, Dnxt, pres, keep, meta, tb, kbox, out,
                                          p*CH, (p+1)*CH, 16, (p==NPH-1) ? 1 : 0);
    if (p < NPH-1)
      cross2_k<CH><<<dim3(CH/256, 8, NB), 256, 0, stream>>>(tb, kbox, meta, pres, (p+1)*CH);
  }
}

extern "C" void kernel_launch(void* const* d_in, const int* in_sizes, int n_in,
                              void* d_out, int out_size, void* d_ws, size_t ws_size,
                              hipStream_t stream){
  (void)in_sizes; (void)n_in; (void)out_size;
  const float* scores = (const float*)d_in[0];
  const float* deltas = (const float*)d_in[1];
  const float* iminfo = (const float*)d_in[2];
  float* out = (float*)d_out;
  char* ws = (char*)d_ws;

  uint32_t* hist  = (uint32_t*)(ws + OFF_HIST);
  uint32_t* meta  = (uint32_t*)(ws + OFF_META);
  uint64_t* cand  = (uint64_t*)(ws + OFF_CAND);
  float*    tb    = (float*)   (ws + OFF_TB);
  uint32_t* keep  = (uint32_t*)(ws + OFF_KEEP);
  uint64_t* pres  = (uint64_t*)(ws + OFF_PRES);

  hipMemsetAsync(ws + OFF_HIST, 0, SZ_HIST + SZ_META, stream);
  hipMemsetAsync(ws + OFF_CAND, 0xFF, SZ_CAND, stream);

  prep_k    <<<(NB*NTOT+255)/256, 256, 0, stream>>>(scores, hist, pres);
  scanhist_k<<<NB, 1024, 0, stream>>>(hist, meta);
  gather_k  <<<NB*NTOT/256, 256, 0, stream>>>(scores, meta, cand);

  bsort_local_k<<<NB*8, 256, 0, stream>>>(cand);
  bsort_gfin_k <<<NB, 1024, 0, stream>>>(cand, deltas, iminfo, tb);

  {
    const size_t szd4 = (size_t)NB*4096*8;             // 524,288
    const size_t szm4 = (size_t)NB*4096*(4096/64)*8;   // 33,554,432
    const size_t need4 = (size_t)OFF_M + 2*szd4 + 2*szm4 + SZ_KBOX;
    if (ws_size >= need4){
      uint64_t* D0   = (uint64_t*)(ws + OFF_M);
      uint64_t* D1   = (uint64_t*)(ws + OFF_M + szd4);
      uint64_t* M0   = (uint64_t*)(ws + OFF_M + 2*szd4);
      uint64_t* M1   = (uint64_t*)(ws + OFF_M + 2*szd4 + szm4);
      float*    kbox = (float*)   (ws + OFF_M + 2*szd4 + 2*szm4);
      run_nms<4096>(M0, D0, M1, D1, pres, keep, meta, tb, kbox, out, stream);
    } else {
      const size_t szd2 = (size_t)NB*2048*8;           // 262,144
      const size_t szm2 = (size_t)NB*2048*(2048/64)*8; // 8,388,608
      uint64_t* D0   = (uint64_t*)(ws + OFF_M);
      uint64_t* D1   = (uint64_t*)(ws + OFF_M + szd2);
      uint64_t* M0   = (uint64_t*)(ws + OFF_M + 2*szd2);
      uint64_t* M1   = (uint64_t*)(ws + OFF_M + 2*szd2 + szm2);
      float*    kbox = (float*)   (ws + OFF_M + 2*szd2 + 2*szm2);
      run_nms<2048>(M0, D0, M1, D1, pres, keep, meta, tb, kbox, out, stream);
    }
  }
}

// Round 23
// 1521.495 us; speedup vs baseline: 1.3952x; 1.0133x over previous
//
#include <hip/hip_runtime.h>
#include <stdint.h>
#include <math.h>

#define NB   16
#define HF   128
#define WF   128
#define NA   9
#define HW   (HF*WF)          // 16384
#define NTOT (HW*NA)          // 147456
#define PRE  12000
#define POST 2000
#define CAP  16384

// fixed ws offsets (bytes); diag + M planes follow, sized by CHUNK at runtime
#define OFF_HIST  0u
#define SZ_HIST   (NB*65536u*4u)            // 4,194,304
#define OFF_META  (OFF_HIST + SZ_HIST)
#define SZ_META   4096u   // words: [0..15] cutoff | [32..47] nk | [256+b*16] gather count
#define OFF_CAND  (OFF_META + SZ_META)
#define SZ_CAND   (NB*CAP*8u)               // 2,097,152
#define OFF_TB    (OFF_CAND + SZ_CAND)
#define SZ_TB     (5u*NB*PRE*4u)            // 3,840,000
#define OFF_KEEP  (OFF_TB + SZ_TB)
#define SZ_KEEP   (NB*POST*4u)              // 128,000
#define OFF_PRES  (OFF_KEEP + SZ_KEEP)
#define SZ_PRES   (NB*64u*8u)               // 8,192 (max NW=64)
#define OFF_M     (OFF_PRES + SZ_PRES)      // = 10,271,744 (16B aligned)
#define SZ_KBOX   (5u*NB*POST*4u)           // 640,000

#define M_CNT(b)  (256 + (b)*16)

// base anchors = classic py-faster-rcnn table minus 1 (base [0,0,15,15]); a8.y2=359.
__constant__ float c_ax1[NA] = {-84.f,-176.f,-360.f,-56.f,-120.f,-248.f,-36.f,-80.f,-168.f};
__constant__ float c_ay1[NA] = {-40.f,-88.f,-184.f,-56.f,-120.f,-248.f,-80.f,-168.f,-344.f};
__constant__ float c_ax2[NA] = { 99.f, 191.f, 375.f, 71.f, 135.f, 263.f, 51.f, 95.f, 183.f};
__constant__ float c_ay2[NA] = { 55.f, 103.f, 199.f, 71.f, 135.f, 263.f, 95.f, 183.f, 359.f};

__device__ __forceinline__ uint32_t score_key(float f){
  uint32_t b = __float_as_uint(f);
  uint32_t u = (b & 0x80000000u) ? ~b : (b | 0x80000000u);
  return ~u;
}

__device__ __forceinline__ bool iou_gt(float ax1,float ay1,float ax2,float ay2,float aa,
                                       float bx1,float by1,float bx2,float by2,float ba){
  float xx1 = fmaxf(ax1,bx1);
  float yy1 = fmaxf(ay1,by1);
  float xx2 = fminf(ax2,bx2);
  float yy2 = fminf(ay2,by2);
  float w = fmaxf(__fadd_rn(__fsub_rn(xx2,xx1),1.0f), 0.0f);
  float h = fmaxf(__fadd_rn(__fsub_rn(yy2,yy1),1.0f), 0.0f);
  float inter = __fmul_rn(w,h);
  float denom = __fsub_rn(__fadd_rn(aa,ba), inter);
  float iou   = __fdiv_rn(inter, denom);
  return iou > 0.7f;
}

// -------- pass 1: histogram (+ zero presup) --------
__global__ void prep_k(const float* __restrict__ scores, uint32_t* __restrict__ hist,
                       uint64_t* __restrict__ presup){
  if (blockIdx.x == 0 && threadIdx.x < 256){
    #pragma unroll
    for (int k=0;k<4;k++) presup[threadIdx.x*4+k] = 0ULL;
  }
  int g = blockIdx.x*256 + threadIdx.x;
  if (g >= NB*NTOT) return;
  int hw = g & (HW-1);
  int t  = g >> 14;
  int ch = t % NA;
  int b  = t / NA;
  float s = scores[((size_t)(b*2*NA + NA + ch) << 14) + hw];
  uint32_t k = score_key(s);
  atomicAdd(&hist[((uint32_t)b<<16) + (k>>16)], 1u);
}

// -------- pass 2: cutoff --------
__global__ __launch_bounds__(1024) void scanhist_k(const uint32_t* __restrict__ hist,
                                                   uint32_t* __restrict__ meta){
  int b = blockIdx.x, t = threadIdx.x;
  const uint32_t* hh = hist + ((uint32_t)b<<16);
  int base = t<<6;
  uint32_t s=0;
  for (int i=0;i<64;i++) s += hh[base+i];
  __shared__ uint32_t part[1024];
  part[t]=s; __syncthreads();
  for (int off=1; off<1024; off<<=1){
    uint32_t v = (t>=off)? part[t-off] : 0u;
    __syncthreads();
    part[t] += v;
    __syncthreads();
  }
  uint32_t incl = part[t], excl = incl - s;
  if (excl < PRE && incl >= PRE){
    uint32_t run = excl;
    for (int i=0;i<64;i++){
      run += hh[base+i];
      if (run >= PRE){ meta[b] = (uint32_t)(base+i); break; }
    }
  }
}

// -------- pass 3: gather (block-aggregated atomics) --------
__global__ __launch_bounds__(256) void gather_k(const float* __restrict__ scores,
                                                uint32_t* __restrict__ meta,
                                                uint64_t* __restrict__ cand){
  int g = blockIdx.x*256 + threadIdx.x;
  int hw = g & (HW-1);
  int t  = g >> 14;
  int ch = t % NA;
  int b  = t / NA;
  float s = scores[((size_t)(b*2*NA + NA + ch) << 14) + hw];
  uint32_t k = score_key(s);
  bool sel = (k>>16) <= meta[b];
  unsigned long long m = __ballot(sel);
  int wid  = threadIdx.x >> 6;
  int lane = threadIdx.x & 63;
  __shared__ uint32_t woff[4];
  __shared__ uint32_t sbase;
  if (lane==0) woff[wid] = __popcll(m);
  __syncthreads();
  if (threadIdx.x==0){
    uint32_t a=0;
    #pragma unroll
    for (int i=0;i<4;i++){ uint32_t c=woff[i]; woff[i]=a; a+=c; }
    sbase = a ? atomicAdd(&meta[M_CNT(b)], a) : 0u;
  }
  __syncthreads();
  if (sel){
    uint32_t pos = sbase + woff[wid] + (uint32_t)__popcll(m & ((1ULL<<lane)-1ULL));
    if (pos < CAP){
      uint32_t idx = (uint32_t)hw*NA + (uint32_t)ch;
      cand[((size_t)b<<14) + pos] = ((uint64_t)k << 18) | (uint64_t)idx;
    }
  }
}

// ======== pass 4a: per-2048-chunk LDS bitonic sort (k=2..2048) ========
__global__ __launch_bounds__(256) void bsort_local_k(uint64_t* __restrict__ buf){
  __shared__ uint64_t S[2048];
  int blk = blockIdx.x;
  int b = blk>>3, chunk = blk&7;
  uint64_t* A_ = buf + ((size_t)b<<14) + ((size_t)chunk<<11);
  int t = threadIdx.x;
  int gbase = chunk<<11;
  for (int i=t;i<2048;i+=256) S[i]=A_[i];
  __syncthreads();
  for (unsigned k=2;k<=2048u;k<<=1){
    for (unsigned j=k>>1;j>0;j>>=1){
      for (int i=t;i<2048;i+=256){
        int l = i ^ (int)j;
        if (l > i){
          bool asc = (((gbase+i) & (int)k)==0);
          uint64_t a=S[i], c=S[l];
          bool sw = asc ? (a>c) : (a<c);
          if (sw){ S[i]=c; S[l]=a; }
        }
      }
      __syncthreads();
    }
  }
  for (int i=t;i<2048;i+=256) A_[i]=S[i];
}

// ======== pass 4b: finish sort (k=4096..16384) + inline extract (1 block/batch) ========
__global__ __launch_bounds__(1024) void bsort_gfin_k(uint64_t* __restrict__ buf,
                                                     const float* __restrict__ deltas,
                                                     const float* __restrict__ iminfo,
                                                     float* __restrict__ tb){
  __shared__ uint64_t S[2048];
  int b = blockIdx.x;
  uint64_t* A_ = buf + ((size_t)b<<14);
  int t = threadIdx.x;
  for (int k = 4096; k <= 16384; k <<= 1){
    for (int j = k>>1; j >= 2048; j >>= 1){
      for (int q = t; q < 8192; q += 1024){
        int i = ((q & ~(j-1))<<1) | (q & (j-1));
        int l = i + j;
        uint64_t a = A_[i], c = A_[l];
        bool asc = ((i & k)==0);
        if (asc ? (a>c) : (a<c)){ A_[i]=c; A_[l]=a; }
      }
      __syncthreads();
    }
    for (int c0 = 0; c0 < 8; c0++){
      uint64_t* C_ = A_ + (c0<<11);
      S[t] = C_[t]; S[t+1024] = C_[t+1024];
      __syncthreads();
      bool asc = (((c0<<11) & k)==0);
      for (int j = 1024; j >= 1; j >>= 1){
        int i = ((t & ~(j-1))<<1) | (t & (j-1));
        int l = i + j;
        uint64_t a=S[i], c=S[l];
        if (asc ? (a>c) : (a<c)){ S[i]=c; S[l]=a; }
        __syncthreads();
      }
      C_[t] = S[t]; C_[t+1024] = S[t+1024];
      __syncthreads();
    }
  }
  float maxx = __fsub_rn(iminfo[b*3+1],1.f);
  float maxy = __fsub_rn(iminfo[b*3+0],1.f);
  for (int j = t; j < PRE; j += 1024){
    uint64_t K = A_[j];
    uint32_t idx = (uint32_t)K & 0x3FFFFu;
    int ch = (int)(idx % NA);
    int hw = (int)(idx / NA);
    int w  = hw & (WF-1);
    int h  = hw >> 7;
    float sx = (float)(w*16), sy = (float)(h*16);
    float ax1 = c_ax1[ch]+sx, ay1 = c_ay1[ch]+sy, ax2 = c_ax2[ch]+sx, ay2 = c_ay2[ch]+sy;
    const float* dp = deltas + ((size_t)(b*4*NA + ch*4) << 14) + hw;
    float dx = dp[0], dy = dp[HW], dwv = dp[2*HW], dhv = dp[3*HW];
    float aw  = __fadd_rn(__fsub_rn(ax2,ax1),1.f);
    float ah  = __fadd_rn(__fsub_rn(ay2,ay1),1.f);
    float acx = __fadd_rn(ax1, __fmul_rn(0.5f,aw));
    float acy = __fadd_rn(ay1, __fmul_rn(0.5f,ah));
    float pcx = __fadd_rn(__fmul_rn(dx,aw), acx);
    float pcy = __fadd_rn(__fmul_rn(dy,ah), acy);
    float ew  = (float)exp((double)dwv);
    float eh  = (float)exp((double)dhv);
    float pw  = __fmul_rn(ew, aw);
    float ph  = __fmul_rn(eh, ah);
    float hx  = __fmul_rn(0.5f,pw), hy = __fmul_rn(0.5f,ph);
    float x1 = __fsub_rn(pcx,hx), y1 = __fsub_rn(pcy,hy);
    float x2 = __fadd_rn(pcx,hx), y2 = __fadd_rn(pcy,hy);
    x1 = fminf(fmaxf(x1,0.f),maxx); y1 = fminf(fmaxf(y1,0.f),maxy);
    x2 = fminf(fmaxf(x2,0.f),maxx); y2 = fminf(fmaxf(y2,0.f),maxy);
    float area = __fmul_rn(__fadd_rn(__fsub_rn(x2,x1),1.f), __fadd_rn(__fsub_rn(y2,y1),1.f));
    int o = b*PRE + j;
    tb[o]            = x1;
    tb[NB*PRE + o]   = y1;
    tb[2*NB*PRE + o] = x2;
    tb[3*NB*PRE + o] = y2;
    tb[4*NB*PRE + o] = area;
  }
}

// -------- NMS phase a: 2D-tiled cross (cand-tile x keep-tile), atomicOr merge --------
template<int CH>
__global__ __launch_bounds__(256) void cross2_k(const float* __restrict__ tb,
                                                const float* __restrict__ kbox,
                                                const uint32_t* __restrict__ meta,
                                                uint64_t* __restrict__ presup,
                                                int base){
  constexpr int NW = CH/64;
  int b  = blockIdx.z;
  int nk = (int)meta[32+b];
  int kt = blockIdx.y*256;
  if (kt >= nk) return;
  __shared__ float kx1[256],ky1[256],kx2[256],ky2[256],kar[256];
  int tt = threadIdx.x;
  int kk = kt + tt;
  if (kk < nk){
    int o = b*POST + kk;
    kx1[tt]=kbox[o];
    ky1[tt]=kbox[NB*POST+o];
    kx2[tt]=kbox[2*NB*POST+o];
    ky2[tt]=kbox[3*NB*POST+o];
    kar[tt]=kbox[4*NB*POST+o];
  }
  __syncthreads();
  int jl = blockIdx.x*256 + tt;
  int j  = base + jl;
  bool supp = false;
  if (j < PRE){
    int o = b*PRE + j;
    float x1=tb[o], y1=tb[NB*PRE+o], x2=tb[2*NB*PRE+o], y2=tb[3*NB*PRE+o], ar=tb[4*NB*PRE+o];
    int lim = min(256, nk-kt);
    for (int q=0;q<lim;q++){
      if (iou_gt(kx1[q],ky1[q],kx2[q],ky2[q],kar[q], x1,y1,x2,y2,ar)){ supp=true; break; }
    }
  }
  unsigned long long m = __ballot(supp);
  if ((tt & 63)==0 && m)
    atomicOr((unsigned long long*)&presup[b*NW + (jl>>6)], m);
}

// -------- fused: scan(phase p, direct-global diag + prefetch) ∥ intra(512-col windows) --------
template<int CH>
__global__ __launch_bounds__(256) void fused_k(const uint64_t* __restrict__ Mscan,
                                               const uint64_t* __restrict__ diagc,
                                               uint64_t* __restrict__ Mnext,
                                               uint64_t* __restrict__ diagn,
                                               uint64_t* __restrict__ presup,
                                               uint32_t* __restrict__ keep,
                                               uint32_t* __restrict__ meta,
                                               const float* __restrict__ tb,
                                               float* __restrict__ kbox,
                                               float* __restrict__ outp,
                                               int base_scan, int base_next, int nscan,
                                               int dofinal){
  constexpr int NW    = CH/64;     // words per row
  constexpr int UNITS = CH/256;    // row-groups per batch
  constexpr int WCOLS = 512;       // cols per intra window block
  constexpr int NWIN  = CH/WCOLS;  // windows per chunk
  constexpr int WPW   = WCOLS/64;  // words per window (8)
  __shared__ __align__(16) char smem[10240];   // intra: 8KB sbx + 2KB sar; scan: none
  __shared__ int s_nk;
  int t = threadIdx.x;

  if ((int)blockIdx.x < nscan){
    // ===== scan role: diag read direct from global (coalesced), prefetched =====
    int b = blockIdx.x;
    int l = t & 63, wv = t >> 6;
    const uint64_t* Mb = Mscan + (size_t)b*CH*NW;
    const uint64_t* Db = diagc + (size_t)b*CH;
    int nk0 = (int)meta[32+b];
    int nk = nk0;
    if (wv==0){
      uint64_t acc = (l<NW) ? presup[b*NW + l] : ~0ULL;
      uint64_t tile = Db[l];                   // word 0, coalesced
      for (int w=0; w<NW; w++){
        if (nk >= POST) break;
        uint64_t tile_nx = (w+1<NW) ? Db[((w+1)<<6) + l] : 0ULL;  // prefetch
        uint64_t cur  = __shfl(acc, w);
        uint64_t kmask = 0;
        while (cur != ~0ULL && nk < POST){
          int p = __ffsll((unsigned long long)(~cur)) - 1;
          if (l==0) keep[b*POST+nk] = (uint32_t)(base_scan + (w<<6) + p);
          nk++;
          kmask |= (1ULL<<p);
          cur |= (1ULL<<p) | (uint64_t)__shfl(tile, p);
        }
        // batched row-OR (upper-triangle only: words l >= w exist)
        bool lok = (l < NW) && (l >= w);
        while (kmask){
          int ps[16];
          #pragma unroll
          for (int i2=0;i2<16;i2++){
            if (kmask){ ps[i2] = __ffsll((unsigned long long)kmask)-1; kmask &= kmask-1ULL; }
            else ps[i2] = -1;
          }
          uint64_t r = 0;
          #pragma unroll
          for (int i2=0;i2<16;i2++){
            uint64_t v = (ps[i2]>=0 && lok) ? Mb[(size_t)((w<<6)+ps[i2])*NW + l] : 0ULL;
            r |= v;
          }
          acc |= r;
        }
        tile = tile_nx;
      }
      if (l==0){ meta[32+b] = (uint32_t)nk; s_nk = nk; }
      if (l<NW){
        long rem = (long)PRE - (long)(base_next + (l<<6));
        uint64_t v = (rem >= 64) ? 0ULL : ((rem <= 0) ? ~0ULL : ~((1ULL<<rem) - 1ULL));
        presup[b*NW + l] = v;
      }
    }
    __syncthreads();
    int nkf = s_nk;
    for (int i = nk0 + t; i < nkf; i += 256){
      int j = (int)keep[b*POST+i];
      int o = b*PRE + j;
      int d = b*POST + i;
      kbox[d]            = tb[o];
      kbox[NB*POST + d]  = tb[NB*PRE+o];
      kbox[2*NB*POST + d]= tb[2*NB*PRE+o];
      kbox[3*NB*POST + d]= tb[3*NB*PRE+o];
      kbox[4*NB*POST + d]= tb[4*NB*PRE+o];
    }
    if (dofinal){
      for (int i = t; i < POST; i += 256){
        float x1=0.f,y1=0.f,x2=0.f,y2=0.f;
        if (i < nkf){
          int j = (int)keep[b*POST+i];
          int o = b*PRE + j;
          x1=tb[o]; y1=tb[NB*PRE+o]; x2=tb[2*NB*PRE+o]; y2=tb[3*NB*PRE+o];
        }
        float* op = outp + (size_t)(b*POST+i)*5;
        op[0]=(float)b; op[1]=x1; op[2]=y1; op[3]=x2; op[4]=y2;
      }
    }
  } else {
    // ===== intra role: window-split bit-matrix, upper-triangle writes only =====
    float4* sbx = (float4*)smem;               // 8 KB (512 col boxes)
    float*  sar = (float*)(smem + 8192);       // 2 KB
    int bid = (int)blockIdx.x - nscan;         // in [0, NB*UNITS*NWIN)
    int b   = bid / (UNITS*NWIN);
    int rem = bid % (UNITS*NWIN);
    int rg  = rem / NWIN;
    int win = rem % NWIN;
    int il  = rg*256 + t;
    int base = base_next;
    int i = base + il;
    bool valid = (i < PRE);
    int w0 = il >> 6;
    int wlo = win*WPW, whi = wlo + WPW;
    if (!valid && win == 0) diagn[(size_t)b*CH + il] = 0ULL;
    // stage this window's columns
    for (int s = t; s < WCOLS; s += 256){
      int j = base + win*WCOLS + s;
      if (j < PRE){
        int o = b*PRE + j;
        sbx[s] = make_float4(tb[o], tb[NB*PRE+o], tb[2*NB*PRE+o], tb[3*NB*PRE+o]);
        sar[s] = tb[4*NB*PRE+o];
      } else { sbx[s] = make_float4(0.f,0.f,-10.f,-10.f); sar[s] = 1.f; }
    }
    __syncthreads();
    if (!valid || whi <= w0) return;
    float4 bb;
    float  ar;
    {
      int o = b*PRE + i;
      bb = make_float4(tb[o], tb[NB*PRE+o], tb[2*NB*PRE+o], tb[3*NB*PRE+o]);
      ar = tb[4*NB*PRE+o];
    }
    uint64_t* Mr = Mnext + (((size_t)b*CH) + (size_t)il)*NW;
    int jmax = PRE - base;
    int wstart = (w0 > wlo) ? w0 : wlo;
    for (int w=wstart; w<whi; w++){
      uint64_t bits = 0;
      int jb = (w<<6) - win*WCOLS;
      #pragma unroll 8
      for (int q=0; q<64; q++){
        int jl = jb + q;
        float4 cb = sbx[jl];
        bool ss = ((w<<6)+q < jmax) && iou_gt(bb.x,bb.y,bb.z,bb.w,ar, cb.x,cb.y,cb.z,cb.w,sar[jl]);
        bits |= ((uint64_t)ss) << q;
      }
      Mr[w] = bits;
      if (w == w0) diagn[(size_t)b*CH + il] = bits;
    }
  }
}

template<int CH>
static void run_nms(uint64_t* M0, uint64_t* D0, uint64_t* M1, uint64_t* D1,
                    uint64_t* pres, uint32_t* keep, uint32_t* meta,
                    const float* tb, float* kbox, float* out, hipStream_t stream){
  constexpr int NPH   = (PRE + CH - 1)/CH;
  constexpr int UNITS = CH/256;
  constexpr int NWIN  = CH/512;
  constexpr int INTRA = NB*UNITS*NWIN;
  // prologue: intra for phase 0 only (presup_0 zeroed by prep_k = all-valid)
  fused_k<CH><<<INTRA, 256, 0, stream>>>(M1, D1, M0, D0, pres, keep, meta, tb, kbox, out, 0, 0, 0, 0);
  for (int p=0; p<NPH; p++){
    uint64_t* Mcur = (p&1) ? M1 : M0;
    uint64_t* Dcur = (p&1) ? D1 : D0;
    uint64_t* Mnxt = (p&1) ? M0 : M1;
    uint64_t* Dnxt = (p&1) ? D0 : D1;
    int nblk = (p < NPH-1) ? (16 + INTRA) : 16;
    fused_k<CH><<<nblk, 256, 0, stream>>>(Mcur, Dcur, Mnxt, Dnxt, pres, keep, meta, tb, kbox, out,
                                          p*CH, (p+1)*CH, 16, (p==NPH-1) ? 1 : 0);
    if (p < NPH-1)
      cross2_k<CH><<<dim3(CH/256, 8, NB), 256, 0, stream>>>(tb, kbox, meta, pres, (p+1)*CH);
  }
}

extern "C" void kernel_launch(void* const* d_in, const int* in_sizes, int n_in,
                              void* d_out, int out_size, void* d_ws, size_t ws_size,
                              hipStream_t stream){
  (void)in_sizes; (void)n_in; (void)out_size;
  const float* scores = (const float*)d_in[0];
  const float* deltas = (const float*)d_in[1];
  const float* iminfo = (const float*)d_in[2];
  float* out = (float*)d_out;
  char* ws = (char*)d_ws;

  uint32_t* hist  = (uint32_t*)(ws + OFF_HIST);
  uint32_t* meta  = (uint32_t*)(ws + OFF_META);
  uint64_t* cand  = (uint64_t*)(ws + OFF_CAND);
  float*    tb    = (float*)   (ws + OFF_TB);
  uint32_t* keep  = (uint32_t*)(ws + OFF_KEEP);
  uint64_t* pres  = (uint64_t*)(ws + OFF_PRES);

  hipMemsetAsync(ws + OFF_HIST, 0, SZ_HIST + SZ_META, stream);
  hipMemsetAsync(ws + OFF_CAND, 0xFF, SZ_CAND, stream);

  prep_k    <<<(NB*NTOT+255)/256, 256, 0, stream>>>(scores, hist, pres);
  scanhist_k<<<NB, 1024, 0, stream>>>(hist, meta);
  gather_k  <<<NB*NTOT/256, 256, 0, stream>>>(scores, meta, cand);

  bsort_local_k<<<NB*8, 256, 0, stream>>>(cand);
  bsort_gfin_k <<<NB, 1024, 0, stream>>>(cand, deltas, iminfo, tb);

  {
    const size_t szd4 = (size_t)NB*4096*8;             // 524,288
    const size_t szm4 = (size_t)NB*4096*(4096/64)*8;   // 33,554,432
    const size_t need4 = (size_t)OFF_M + 2*szd4 + 2*szm4 + SZ_KBOX;
    if (ws_size >= need4){
      uint64_t* D0   = (uint64_t*)(ws + OFF_M);
      uint64_t* D1   = (uint64_t*)(ws + OFF_M + szd4);
      uint64_t* M0   = (uint64_t*)(ws + OFF_M + 2*szd4);
      uint64_t* M1   = (uint64_t*)(ws + OFF_M + 2*szd4 + szm4);
      float*    kbox = (float*)   (ws + OFF_M + 2*szd4 + 2*szm4);
      run_nms<4096>(M0, D0, M1, D1, pres, keep, meta, tb, kbox, out, stream);
    } else {
      const size_t szd2 = (size_t)NB*2048*8;           // 262,144
      const size_t szm2 = (size_t)NB*2048*(2048/64)*8; // 8,388,608
      uint64_t* D0   = (uint64_t*)(ws + OFF_M);
      uint64_t* D1   = (uint64_t*)(ws + OFF_M + szd2);
      uint64_t* M0   = (uint64_t*)(ws + OFF_M + 2*szd2);
      uint64_t* M1   = (uint64_t*)(ws + OFF_M + 2*szd2 + szm2);
      float*    kbox = (float*)   (ws + OFF_M + 2*szd2 + 2*szm2);
      run_nms<2048>(M0, D0, M1, D1, pres, keep, meta, tb, kbox, out, stream);
    }
  }
}

// Round 24
// 1505.619 us; speedup vs baseline: 1.4099x; 1.0105x over previous
//
#include <hip/hip_runtime.h>
#include <stdint.h>
#include <math.h>

#define NB   16
#define HF   128
#define WF   128
#define NA   9
#define HW   (HF*WF)          // 16384
#define NTOT (HW*NA)          // 147456
#define PRE  12000
#define POST 2000
#define CAP  16384

// fixed ws offsets (bytes); diag + M planes follow, sized by CHUNK at runtime
#define OFF_HIST  0u
#define SZ_HIST   (NB*65536u*4u)            // 4,194,304
#define OFF_META  (OFF_HIST + SZ_HIST)
#define SZ_META   4096u   // words: [0..15] cutoff | [32..47] nk | [256+b*16] gather count
#define OFF_CAND  (OFF_META + SZ_META)
#define SZ_CAND   (NB*CAP*8u)               // 2,097,152
#define OFF_TB    (OFF_CAND + SZ_CAND)
#define SZ_TB     (5u*NB*PRE*4u)            // 3,840,000
#define OFF_KEEP  (OFF_TB + SZ_TB)
#define SZ_KEEP   (NB*POST*4u)              // 128,000
#define OFF_PRES  (OFF_KEEP + SZ_KEEP)
#define SZ_PRES   (NB*64u*8u)               // 8,192 (max NW=64)
#define OFF_M     (OFF_PRES + SZ_PRES)      // = 10,271,744 (16B aligned)
#define SZ_KBOX   (5u*NB*POST*4u)           // 640,000

#define M_CNT(b)  (256 + (b)*16)

// base anchors = classic py-faster-rcnn table minus 1 (base [0,0,15,15]); a8.y2=359.
__constant__ float c_ax1[NA] = {-84.f,-176.f,-360.f,-56.f,-120.f,-248.f,-36.f,-80.f,-168.f};
__constant__ float c_ay1[NA] = {-40.f,-88.f,-184.f,-56.f,-120.f,-248.f,-80.f,-168.f,-344.f};
__constant__ float c_ax2[NA] = { 99.f, 191.f, 375.f, 71.f, 135.f, 263.f, 51.f, 95.f, 183.f};
__constant__ float c_ay2[NA] = { 55.f, 103.f, 199.f, 71.f, 135.f, 263.f, 95.f, 183.f, 359.f};

__device__ __forceinline__ uint32_t score_key(float f){
  uint32_t b = __float_as_uint(f);
  uint32_t u = (b & 0x80000000u) ? ~b : (b | 0x80000000u);
  return ~u;
}

__device__ __forceinline__ bool iou_gt(float ax1,float ay1,float ax2,float ay2,float aa,
                                       float bx1,float by1,float bx2,float by2,float ba){
  float xx1 = fmaxf(ax1,bx1);
  float yy1 = fmaxf(ay1,by1);
  float xx2 = fminf(ax2,bx2);
  float yy2 = fminf(ay2,by2);
  float w = fmaxf(__fadd_rn(__fsub_rn(xx2,xx1),1.0f), 0.0f);
  float h = fmaxf(__fadd_rn(__fsub_rn(yy2,yy1),1.0f), 0.0f);
  float inter = __fmul_rn(w,h);
  float denom = __fsub_rn(__fadd_rn(aa,ba), inter);
  float iou   = __fdiv_rn(inter, denom);
  return iou > 0.7f;
}

// -------- pass 1: histogram (+ zero presup) --------
__global__ void prep_k(const float* __restrict__ scores, uint32_t* __restrict__ hist,
                       uint64_t* __restrict__ presup){
  if (blockIdx.x == 0 && threadIdx.x < 256){
    #pragma unroll
    for (int k=0;k<4;k++) presup[threadIdx.x*4+k] = 0ULL;
  }
  int g = blockIdx.x*256 + threadIdx.x;
  if (g >= NB*NTOT) return;
  int hw = g & (HW-1);
  int t  = g >> 14;
  int ch = t % NA;
  int b  = t / NA;
  float s = scores[((size_t)(b*2*NA + NA + ch) << 14) + hw];
  uint32_t k = score_key(s);
  atomicAdd(&hist[((uint32_t)b<<16) + (k>>16)], 1u);
}

// -------- pass 2: cutoff --------
__global__ __launch_bounds__(1024) void scanhist_k(const uint32_t* __restrict__ hist,
                                                   uint32_t* __restrict__ meta){
  int b = blockIdx.x, t = threadIdx.x;
  const uint32_t* hh = hist + ((uint32_t)b<<16);
  int base = t<<6;
  uint32_t s=0;
  for (int i=0;i<64;i++) s += hh[base+i];
  __shared__ uint32_t part[1024];
  part[t]=s; __syncthreads();
  for (int off=1; off<1024; off<<=1){
    uint32_t v = (t>=off)? part[t-off] : 0u;
    __syncthreads();
    part[t] += v;
    __syncthreads();
  }
  uint32_t incl = part[t], excl = incl - s;
  if (excl < PRE && incl >= PRE){
    uint32_t run = excl;
    for (int i=0;i<64;i++){
      run += hh[base+i];
      if (run >= PRE){ meta[b] = (uint32_t)(base+i); break; }
    }
  }
}

// -------- pass 3: gather (block-aggregated atomics) --------
__global__ __launch_bounds__(256) void gather_k(const float* __restrict__ scores,
                                                uint32_t* __restrict__ meta,
                                                uint64_t* __restrict__ cand){
  int g = blockIdx.x*256 + threadIdx.x;
  int hw = g & (HW-1);
  int t  = g >> 14;
  int ch = t % NA;
  int b  = t / NA;
  float s = scores[((size_t)(b*2*NA + NA + ch) << 14) + hw];
  uint32_t k = score_key(s);
  bool sel = (k>>16) <= meta[b];
  unsigned long long m = __ballot(sel);
  int wid  = threadIdx.x >> 6;
  int lane = threadIdx.x & 63;
  __shared__ uint32_t woff[4];
  __shared__ uint32_t sbase;
  if (lane==0) woff[wid] = __popcll(m);
  __syncthreads();
  if (threadIdx.x==0){
    uint32_t a=0;
    #pragma unroll
    for (int i=0;i<4;i++){ uint32_t c=woff[i]; woff[i]=a; a+=c; }
    sbase = a ? atomicAdd(&meta[M_CNT(b)], a) : 0u;
  }
  __syncthreads();
  if (sel){
    uint32_t pos = sbase + woff[wid] + (uint32_t)__popcll(m & ((1ULL<<lane)-1ULL));
    if (pos < CAP){
      uint32_t idx = (uint32_t)hw*NA + (uint32_t)ch;
      cand[((size_t)b<<14) + pos] = ((uint64_t)k << 18) | (uint64_t)idx;
    }
  }
}

// ======== pass 4a: per-2048-chunk LDS bitonic sort (k=2..2048) ========
__global__ __launch_bounds__(256) void bsort_local_k(uint64_t* __restrict__ buf){
  __shared__ uint64_t S[2048];
  int blk = blockIdx.x;
  int b = blk>>3, chunk = blk&7;
  uint64_t* A_ = buf + ((size_t)b<<14) + ((size_t)chunk<<11);
  int t = threadIdx.x;
  int gbase = chunk<<11;
  for (int i=t;i<2048;i+=256) S[i]=A_[i];
  __syncthreads();
  for (unsigned k=2;k<=2048u;k<<=1){
    for (unsigned j=k>>1;j>0;j>>=1){
      for (int i=t;i<2048;i+=256){
        int l = i ^ (int)j;
        if (l > i){
          bool asc = (((gbase+i) & (int)k)==0);
          uint64_t a=S[i], c=S[l];
          bool sw = asc ? (a>c) : (a<c);
          if (sw){ S[i]=c; S[l]=a; }
        }
      }
      __syncthreads();
    }
  }
  for (int i=t;i<2048;i+=256) A_[i]=S[i];
}

// ======== pass 4b: finish sort (k=4096..16384) + inline extract (1 block/batch) ========
__global__ __launch_bounds__(1024) void bsort_gfin_k(uint64_t* __restrict__ buf,
                                                     const float* __restrict__ deltas,
                                                     const float* __restrict__ iminfo,
                                                     float* __restrict__ tb){
  __shared__ uint64_t S[2048];
  int b = blockIdx.x;
  uint64_t* A_ = buf + ((size_t)b<<14);
  int t = threadIdx.x;
  for (int k = 4096; k <= 16384; k <<= 1){
    for (int j = k>>1; j >= 2048; j >>= 1){
      for (int q = t; q < 8192; q += 1024){
        int i = ((q & ~(j-1))<<1) | (q & (j-1));
        int l = i + j;
        uint64_t a = A_[i], c = A_[l];
        bool asc = ((i & k)==0);
        if (asc ? (a>c) : (a<c)){ A_[i]=c; A_[l]=a; }
      }
      __syncthreads();
    }
    for (int c0 = 0; c0 < 8; c0++){
      uint64_t* C_ = A_ + (c0<<11);
      S[t] = C_[t]; S[t+1024] = C_[t+1024];
      __syncthreads();
      bool asc = (((c0<<11) & k)==0);
      for (int j = 1024; j >= 1; j >>= 1){
        int i = ((t & ~(j-1))<<1) | (t & (j-1));
        int l = i + j;
        uint64_t a=S[i], c=S[l];
        if (asc ? (a>c) : (a<c)){ S[i]=c; S[l]=a; }
        __syncthreads();
      }
      C_[t] = S[t]; C_[t+1024] = S[t+1024];
      __syncthreads();
    }
  }
  float maxx = __fsub_rn(iminfo[b*3+1],1.f);
  float maxy = __fsub_rn(iminfo[b*3+0],1.f);
  for (int j = t; j < PRE; j += 1024){
    uint64_t K = A_[j];
    uint32_t idx = (uint32_t)K & 0x3FFFFu;
    int ch = (int)(idx % NA);
    int hw = (int)(idx / NA);
    int w  = hw & (WF-1);
    int h  = hw >> 7;
    float sx = (float)(w*16), sy = (float)(h*16);
    float ax1 = c_ax1[ch]+sx, ay1 = c_ay1[ch]+sy, ax2 = c_ax2[ch]+sx, ay2 = c_ay2[ch]+sy;
    const float* dp = deltas + ((size_t)(b*4*NA + ch*4) << 14) + hw;
    float dx = dp[0], dy = dp[HW], dwv = dp[2*HW], dhv = dp[3*HW];
    float aw  = __fadd_rn(__fsub_rn(ax2,ax1),1.f);
    float ah  = __fadd_rn(__fsub_rn(ay2,ay1),1.f);
    float acx = __fadd_rn(ax1, __fmul_rn(0.5f,aw));
    float acy = __fadd_rn(ay1, __fmul_rn(0.5f,ah));
    float pcx = __fadd_rn(__fmul_rn(dx,aw), acx);
    float pcy = __fadd_rn(__fmul_rn(dy,ah), acy);
    float ew  = (float)exp((double)dwv);
    float eh  = (float)exp((double)dhv);
    float pw  = __fmul_rn(ew, aw);
    float ph  = __fmul_rn(eh, ah);
    float hx  = __fmul_rn(0.5f,pw), hy = __fmul_rn(0.5f,ph);
    float x1 = __fsub_rn(pcx,hx), y1 = __fsub_rn(pcy,hy);
    float x2 = __fadd_rn(pcx,hx), y2 = __fadd_rn(pcy,hy);
    x1 = fminf(fmaxf(x1,0.f),maxx); y1 = fminf(fmaxf(y1,0.f),maxy);
    x2 = fminf(fmaxf(x2,0.f),maxx); y2 = fminf(fmaxf(y2,0.f),maxy);
    float area = __fmul_rn(__fadd_rn(__fsub_rn(x2,x1),1.f), __fadd_rn(__fsub_rn(y2,y1),1.f));
    int o = b*PRE + j;
    tb[o]            = x1;
    tb[NB*PRE + o]   = y1;
    tb[2*NB*PRE + o] = x2;
    tb[3*NB*PRE + o] = y2;
    tb[4*NB*PRE + o] = area;
  }
}

// -------- NMS phase a: 2D-tiled cross (cand-tile x keep-tile), atomicOr merge --------
template<int CH>
__global__ __launch_bounds__(256) void cross2_k(const float* __restrict__ tb,
                                                const float* __restrict__ kbox,
                                                const uint32_t* __restrict__ meta,
                                                uint64_t* __restrict__ presup,
                                                int base){
  constexpr int NW = CH/64;
  int b  = blockIdx.z;
  int nk = (int)meta[32+b];
  int kt = blockIdx.y*256;
  if (kt >= nk) return;
  __shared__ float kx1[256],ky1[256],kx2[256],ky2[256],kar[256];
  int tt = threadIdx.x;
  int kk = kt + tt;
  if (kk < nk){
    int o = b*POST + kk;
    kx1[tt]=kbox[o];
    ky1[tt]=kbox[NB*POST+o];
    kx2[tt]=kbox[2*NB*POST+o];
    ky2[tt]=kbox[3*NB*POST+o];
    kar[tt]=kbox[4*NB*POST+o];
  }
  __syncthreads();
  int jl = blockIdx.x*256 + tt;
  int j  = base + jl;
  bool supp = false;
  if (j < PRE){
    int o = b*PRE + j;
    float x1=tb[o], y1=tb[NB*PRE+o], x2=tb[2*NB*PRE+o], y2=tb[3*NB*PRE+o], ar=tb[4*NB*PRE+o];
    int lim = min(256, nk-kt);
    for (int q=0;q<lim;q++){
      if (iou_gt(kx1[q],ky1[q],kx2[q],ky2[q],kar[q], x1,y1,x2,y2,ar)){ supp=true; break; }
    }
  }
  unsigned long long m = __ballot(supp);
  if ((tt & 63)==0 && m)
    atomicOr((unsigned long long*)&presup[b*NW + (jl>>6)], m);
}

// -------- fused: scan(phase p) ∥ intra(phase p+1) -- M in WORD-MAJOR layout:
//          M[(b*NW + w)*CH + row]  (coalesced intra writes) --------
template<int CH>
__global__ __launch_bounds__(256) void fused_k(const uint64_t* __restrict__ Mscan,
                                               const uint64_t* __restrict__ diagc,
                                               uint64_t* __restrict__ Mnext,
                                               uint64_t* __restrict__ diagn,
                                               uint64_t* __restrict__ presup,
                                               uint32_t* __restrict__ keep,
                                               uint32_t* __restrict__ meta,
                                               const float* __restrict__ tb,
                                               float* __restrict__ kbox,
                                               float* __restrict__ outp,
                                               int base_scan, int base_next, int nscan,
                                               int dofinal){
  constexpr int NW    = CH/64;     // words per row
  constexpr int UNITS = CH/256;    // row-groups per batch
  constexpr int WCOLS = 512;       // cols per intra window block
  constexpr int NWIN  = CH/WCOLS;  // windows per chunk
  constexpr int WPW   = WCOLS/64;  // words per window (8)
  __shared__ __align__(16) char smem[10240];
  __shared__ int s_nk;
  int t = threadIdx.x;

  if ((int)blockIdx.x < nscan){
    // ===== scan role: direct-global diag (prefetched); word-major row-OR =====
    int b = blockIdx.x;
    int l = t & 63, wv = t >> 6;
    const uint64_t* Mb = Mscan + (size_t)b*CH*NW;   // base of batch plane (word-major)
    const uint64_t* Db = diagc + (size_t)b*CH;
    int nk0 = (int)meta[32+b];
    int nk = nk0;
    if (wv==0){
      uint64_t acc = (l<NW) ? presup[b*NW + l] : ~0ULL;
      uint64_t tile = Db[l];
      for (int w=0; w<NW; w++){
        if (nk >= POST) break;
        uint64_t tile_nx = (w+1<NW) ? Db[((w+1)<<6) + l] : 0ULL;
        uint64_t cur  = __shfl(acc, w);
        uint64_t kmask = 0;
        while (cur != ~0ULL && nk < POST){
          int p = __ffsll((unsigned long long)(~cur)) - 1;
          if (l==0) keep[b*POST+nk] = (uint32_t)(base_scan + (w<<6) + p);
          nk++;
          kmask |= (1ULL<<p);
          cur |= (1ULL<<p) | (uint64_t)__shfl(tile, p);
        }
        // batched row-OR: lane l reads M[word=l][row] (upper-triangle: l >= w)
        bool lok = (l < NW) && (l >= w);
        const uint64_t* Ml = Mb + (size_t)l*CH;
        while (kmask){
          int ps[16];
          #pragma unroll
          for (int i2=0;i2<16;i2++){
            if (kmask){ ps[i2] = __ffsll((unsigned long long)kmask)-1; kmask &= kmask-1ULL; }
            else ps[i2] = -1;
          }
          uint64_t r = 0;
          #pragma unroll
          for (int i2=0;i2<16;i2++){
            uint64_t v = (ps[i2]>=0 && lok) ? Ml[(w<<6)+ps[i2]] : 0ULL;
            r |= v;
          }
          acc |= r;
        }
        tile = tile_nx;
      }
      if (l==0){ meta[32+b] = (uint32_t)nk; s_nk = nk; }
      if (l<NW){
        long rem = (long)PRE - (long)(base_next + (l<<6));
        uint64_t v = (rem >= 64) ? 0ULL : ((rem <= 0) ? ~0ULL : ~((1ULL<<rem) - 1ULL));
        presup[b*NW + l] = v;
      }
    }
    __syncthreads();
    int nkf = s_nk;
    for (int i = nk0 + t; i < nkf; i += 256){
      int j = (int)keep[b*POST+i];
      int o = b*PRE + j;
      int d = b*POST + i;
      kbox[d]            = tb[o];
      kbox[NB*POST + d]  = tb[NB*PRE+o];
      kbox[2*NB*POST + d]= tb[2*NB*PRE+o];
      kbox[3*NB*POST + d]= tb[3*NB*PRE+o];
      kbox[4*NB*POST + d]= tb[4*NB*PRE+o];
    }
    if (dofinal){
      for (int i = t; i < POST; i += 256){
        float x1=0.f,y1=0.f,x2=0.f,y2=0.f;
        if (i < nkf){
          int j = (int)keep[b*POST+i];
          int o = b*PRE + j;
          x1=tb[o]; y1=tb[NB*PRE+o]; x2=tb[2*NB*PRE+o]; y2=tb[3*NB*PRE+o];
        }
        float* op = outp + (size_t)(b*POST+i)*5;
        op[0]=(float)b; op[1]=x1; op[2]=y1; op[3]=x2; op[4]=y2;
      }
    }
  } else {
    // ===== intra role: window-split bit-matrix, word-major coalesced writes =====
    float4* sbx = (float4*)smem;               // 8 KB (512 col boxes)
    float*  sar = (float*)(smem + 8192);       // 2 KB
    int bid = (int)blockIdx.x - nscan;
    int b   = bid / (UNITS*NWIN);
    int rem = bid % (UNITS*NWIN);
    int rg  = rem / NWIN;
    int win = rem % NWIN;
    int il  = rg*256 + t;
    int base = base_next;
    int i = base + il;
    bool valid = (i < PRE);
    int w0 = il >> 6;
    int wlo = win*WPW, whi = wlo + WPW;
    if (!valid && win == 0) diagn[(size_t)b*CH + il] = 0ULL;
    for (int s = t; s < WCOLS; s += 256){
      int j = base + win*WCOLS + s;
      if (j < PRE){
        int o = b*PRE + j;
        sbx[s] = make_float4(tb[o], tb[NB*PRE+o], tb[2*NB*PRE+o], tb[3*NB*PRE+o]);
        sar[s] = tb[4*NB*PRE+o];
      } else { sbx[s] = make_float4(0.f,0.f,-10.f,-10.f); sar[s] = 1.f; }
    }
    __syncthreads();
    if (!valid || whi <= w0) return;
    float4 bb;
    float  ar;
    {
      int o = b*PRE + i;
      bb = make_float4(tb[o], tb[NB*PRE+o], tb[2*NB*PRE+o], tb[3*NB*PRE+o]);
      ar = tb[4*NB*PRE+o];
    }
    uint64_t* Mw = Mnext + (size_t)b*NW*CH;    // word-major plane
    int jmax = PRE - base;
    int wstart = (w0 > wlo) ? w0 : wlo;
    for (int w=wstart; w<whi; w++){
      uint64_t bits = 0;
      int jb = (w<<6) - win*WCOLS;
      #pragma unroll 8
      for (int q=0; q<64; q++){
        int jl = jb + q;
        float4 cb = sbx[jl];
        bool ss = ((w<<6)+q < jmax) && iou_gt(bb.x,bb.y,bb.z,bb.w,ar, cb.x,cb.y,cb.z,cb.w,sar[jl]);
        bits |= ((uint64_t)ss) << q;
      }
      Mw[(size_t)w*CH + il] = bits;            // coalesced across lanes
      if (w == w0) diagn[(size_t)b*CH + il] = bits;
    }
  }
}

template<int CH>
static void run_nms(uint64_t* M0, uint64_t* D0, uint64_t* M1, uint64_t* D1,
                    uint64_t* pres, uint32_t* keep, uint32_t* meta,
                    const float* tb, float* kbox, float* out, hipStream_t stream){
  constexpr int NPH   = (PRE + CH - 1)/CH;
  constexpr int UNITS = CH/256;
  constexpr int NWIN  = CH/512;
  constexpr int INTRA = NB*UNITS*NWIN;
  fused_k<CH><<<INTRA, 256, 0, stream>>>(M1, D1, M0, D0, pres, keep, meta, tb, kbox, out, 0, 0, 0, 0);
  for (int p=0; p<NPH; p++){
    uint64_t* Mcur = (p&1) ? M1 : M0;
    uint64_t* Dcur = (p&1) ? D1 : D0;
    uint64_t* Mnxt = (p&1) ? M0 : M1;
    uint64_t* Dnxt = (p&1) ? D0 : D1;
    int nblk = (p < NPH-1) ? (16 + INTRA) : 16;
    fused_k<CH><<<nblk, 256, 0, stream>>>(Mcur, Dcur, Mnxt, Dnxt, pres, keep, meta, tb, kbox, out,
                                          p*CH, (p+1)*CH, 16, (p==NPH-1) ? 1 : 0);
    if (p < NPH-1)
      cross2_k<CH><<<dim3(CH/256, 8, NB), 256, 0, stream>>>(tb, kbox, meta, pres, (p+1)*CH);
  }
}

extern "C" void kernel_launch(void* const* d_in, const int* in_sizes, int n_in,
                              void* d_out, int out_size, void* d_ws, size_t ws_size,
                              hipStream_t stream){
  (void)in_sizes; (void)n_in; (void)out_size;
  const float* scores = (const float*)d_in[0];
  const float* deltas = (const float*)d_in[1];
  const float* iminfo = (const float*)d_in[2];
  float* out = (float*)d_out;
  char* ws = (char*)d_ws;

  uint32_t* hist  = (uint32_t*)(ws + OFF_HIST);
  uint32_t* meta  = (uint32_t*)(ws + OFF_META);
  uint64_t* cand  = (uint64_t*)(ws + OFF_CAND);
  float*    tb    = (float*)   (ws + OFF_TB);
  uint32_t* keep  = (uint32_t*)(ws + OFF_KEEP);
  uint64_t* pres  = (uint64_t*)(ws + OFF_PRES);

  hipMemsetAsync(ws + OFF_HIST, 0, SZ_HIST + SZ_META, stream);
  hipMemsetAsync(ws + OFF_CAND, 0xFF, SZ_CAND, stream);

  prep_k    <<<(NB*NTOT+255)/256, 256, 0, stream>>>(scores, hist, pres);
  scanhist_k<<<NB, 1024, 0, stream>>>(hist, meta);
  gather_k  <<<NB*NTOT/256, 256, 0, stream>>>(scores, meta, cand);

  bsort_local_k<<<NB*8, 256, 0, stream>>>(cand);
  bsort_gfin_k <<<NB, 1024, 0, stream>>>(cand, deltas, iminfo, tb);

  {
    const size_t szd4 = (size_t)NB*4096*8;             // 524,288
    const size_t szm4 = (size_t)NB*4096*(4096/64)*8;   // 33,554,432
    const size_t need4 = (size_t)OFF_M + 2*szd4 + 2*szm4 + SZ_KBOX;
    if (ws_size >= need4){
      uint64_t* D0   = (uint64_t*)(ws + OFF_M);
      uint64_t* D1   = (uint64_t*)(ws + OFF_M + szd4);
      uint64_t* M0   = (uint64_t*)(ws + OFF_M + 2*szd4);
      uint64_t* M1   = (uint64_t*)(ws + OFF_M + 2*szd4 + szm4);
      float*    kbox = (float*)   (ws + OFF_M + 2*szd4 + 2*szm4);
      run_nms<4096>(M0, D0, M1, D1, pres, keep, meta, tb, kbox, out, stream);
    } else {
      const size_t szd2 = (size_t)NB*2048*8;           // 262,144
      const size_t szm2 = (size_t)NB*2048*(2048/64)*8; // 8,388,608
      uint64_t* D0   = (uint64_t*)(ws + OFF_M);
      uint64_t* D1   = (uint64_t*)(ws + OFF_M + szd2);
      uint64_t* M0   = (uint64_t*)(ws + OFF_M + 2*szd2);
      uint64_t* M1   = (uint64_t*)(ws + OFF_M + 2*szd2 + szm2);
      float*    kbox = (float*)   (ws + OFF_M + 2*szd2 + 2*szm2);
      run_nms<2048>(M0, D0, M1, D1, pres, keep, meta, tb, kbox, out, stream);
    }
  }
}